// Round 12
// baseline (502.304 us; speedup 1.0000x reference)
//
#include <hip/hip_runtime.h>
#include <math.h>

// MTGCN R10: plane-split fp8 (two 64B planes per row matrix -> 3.2MB working set
// fits per-XCD L2). Gathers: 2 plane passes, 4-lane slots x 16B, 8-edge unroll.
// Loss: pass0 plane0 dots -> sp[2P]; pass1 plane1 dots (masked) + log-sigmoid.
// Rest as R9: atomic-free CSR (hist2+rank+reduce_base2), bf16 MFMA GEMMs.

typedef unsigned short ushort_t;
typedef unsigned char u8;
typedef __attribute__((ext_vector_type(8))) __bf16 bf16x8;
typedef __attribute__((ext_vector_type(8))) short s16x8;
typedef __attribute__((ext_vector_type(4))) float f32x4;
typedef __attribute__((ext_vector_type(2))) float f32x2;

#define NB_H 256
#define HW 12500
#define PW 25000

__device__ __forceinline__ f32x4 mfma16x16x32(s16x8 a, s16x8 b, f32x4 c) {
  return __builtin_amdgcn_mfma_f32_16x16x32_bf16(
      __builtin_bit_cast(bf16x8, a), __builtin_bit_cast(bf16x8, b), c, 0, 0, 0);
}
__device__ __forceinline__ ushort_t f2bf(float f) {
  union { float f; unsigned u; } c; c.f = f;
  unsigned r = (c.u + 0x7FFFu + ((c.u >> 16) & 1u)) >> 16;
  return (ushort_t)r;
}
__device__ __forceinline__ f32x2 cvt2lo(unsigned u) {
  return __builtin_amdgcn_cvt_pk_f32_fp8((int)u, false);
}
__device__ __forceinline__ f32x2 cvt2hi(unsigned u) {
  return __builtin_amdgcn_cvt_pk_f32_fp8((int)u, true);
}
__device__ __forceinline__ u8 f2fp8(float f) {
  return (u8)(__builtin_amdgcn_cvt_pk_fp8_f32(f, 0.f, 0, false) & 0xff);
}

// =======================================================================
// MFMA GEMM. VAR1/VAR2 fp8 outputs now plane-split: plane stride M*64 bytes.
// =======================================================================
template<int VAR, int NT, int KTOT>
__global__ __launch_bounds__(256) void gemm_mfma(
    const ushort_t* __restrict__ A0, const ushort_t* __restrict__ A1,
    const ushort_t* __restrict__ Wt,
    const float* __restrict__ bias0, const float* __restrict__ bias1,
    const float* __restrict__ x1,
    const float* __restrict__ W3c, const float* __restrict__ b3c,
    void* __restrict__ out0, void* __restrict__ out1,
    float* __restrict__ t0g, float* __restrict__ t1g, int M)
{
  constexpr int NF = NT / 32;
  __shared__ __align__(16) ushort_t As[64 * 40];
  __shared__ __align__(16) ushort_t Bs[NT * 40];
  __shared__ float w3s[400];
  const int tid  = threadIdx.x;
  const int lane = tid & 63, w = tid >> 6;
  const int m0 = blockIdx.x * 64;
  const int wm = (w & 1) * 32, wn = (w >> 1) * (NT / 2);
  const size_t pstride = (size_t)M * 64;   // fp8 plane stride (bytes)
  if (VAR == 2) { for (int i = tid; i < 400; i += 256) w3s[i] = W3c[i]; }
  f32x4 acc[2][NF];
#pragma unroll
  for (int i = 0; i < 2; ++i)
#pragma unroll
    for (int j = 0; j < NF; ++j) acc[i][j] = (f32x4){0.f, 0.f, 0.f, 0.f};

  for (int k0 = 0; k0 < KTOT; k0 += 32) {
    { // A stage
      const int r = tid >> 2, c8 = (tid & 3) * 8;
      const int gm = m0 + r;
      uint4 v = {0u, 0u, 0u, 0u};
      if (gm < M) {
        const ushort_t* srcp;
        if (VAR == 0) srcp = (k0 < 128) ? A0 + (size_t)gm * 128 + k0 + c8
                                        : A1 + (size_t)gm * 128 + (k0 - 128) + c8;
        else if (VAR == 1) srcp = A0 + (size_t)gm * 320 + k0 + c8;
        else srcp = A0 + (size_t)gm * 128 + k0 + c8;
        v = *(const uint4*)srcp;
      }
      *(uint4*)&As[r * 40 + c8] = v;
    }
    { // B stage
      const int c8 = (tid & 3) * 8;
#pragma unroll
      for (int i = 0; i < (NT * 4 + 255) / 256; ++i) {
        const int r = (tid >> 2) + i * 64;
        if (r < NT)
          *(uint4*)&Bs[r * 40 + c8] = *(const uint4*)(Wt + (size_t)r * KTOT + k0 + c8);
      }
    }
    __syncthreads();
    s16x8 af[2], bfr[NF];
#pragma unroll
    for (int mi = 0; mi < 2; ++mi)
      af[mi] = *(const s16x8*)&As[(wm + mi * 16 + (lane & 15)) * 40 + (lane >> 4) * 8];
#pragma unroll
    for (int ni = 0; ni < NF; ++ni)
      bfr[ni] = *(const s16x8*)&Bs[(wn + ni * 16 + (lane & 15)) * 40 + (lane >> 4) * 8];
#pragma unroll
    for (int mi = 0; mi < 2; ++mi)
#pragma unroll
      for (int ni = 0; ni < NF; ++ni)
        acc[mi][ni] = mfma16x16x32(af[mi], bfr[ni], acc[mi][ni]);
    __syncthreads();
  }

  if (VAR == 2) {
#pragma unroll
    for (int mi = 0; mi < 2; ++mi)
#pragma unroll
      for (int r = 0; r < 4; ++r) {
        const int gRow = m0 + wm + mi * 16 + ((lane >> 4) << 2) + r;
        float p0 = 0.f, p1 = 0.f, p2 = 0.f, p3 = 0.f;
#pragma unroll
        for (int ni = 0; ni < NF; ++ni) {
          const int col = wn + ni * 16 + (lane & 15);
          const float v = acc[mi][ni][r];
          if (gRow < M) {
            if (col < 100) {
              const float x2v = x1[(size_t)gRow * 128 + col] + fmaxf(v + bias0[col], 0.f);
              p0 = fmaf(x2v, w3s[col * 2 + 0], p0);
              p1 = fmaf(x2v, w3s[col * 2 + 1], p1);
              p2 = fmaf(x2v, w3s[200 + col * 2 + 0], p2);
              p3 = fmaf(x2v, w3s[200 + col * 2 + 1], p3);
            } else if (col < 200) {
              const int c = col - 100;
              const int pl = (c >= 64);
              ((u8*)out1)[pl * pstride + (size_t)gRow * 64 + (c - pl * 64)] =
                  f2fp8(x1[(size_t)gRow * 128 + c] + fmaxf(v + bias1[c], 0.f));
            }
          }
        }
        if (wn == 0) {
#pragma unroll
          for (int off = 8; off; off >>= 1) {
            p0 += __shfl_down(p0, off, 16);
            p1 += __shfl_down(p1, off, 16);
            p2 += __shfl_down(p2, off, 16);
            p3 += __shfl_down(p3, off, 16);
          }
          if ((lane & 15) == 0 && gRow < M) {
            t0g[(size_t)gRow * 2 + 0] = p0 + b3c[0];
            t0g[(size_t)gRow * 2 + 1] = p1 + b3c[1];
            t1g[(size_t)gRow * 2 + 0] = p2;
            t1g[(size_t)gRow * 2 + 1] = p3;
          }
        }
      }
  } else {
#pragma unroll
    for (int mi = 0; mi < 2; ++mi)
#pragma unroll
      for (int ni = 0; ni < NF; ++ni)
#pragma unroll
        for (int r = 0; r < 4; ++r) {
          const int gRow = m0 + wm + mi * 16 + ((lane >> 4) << 2) + r;
          const int col  = wn + ni * 16 + (lane & 15);
          if (gRow >= M) continue;
          const float v = acc[mi][ni][r];
          if (VAR == 0) {
            ushort_t* h = (ushort_t*)out0;
            h[(size_t)gRow * 320 + col] = (col < 300) ? f2bf(fmaxf(v + bias0[col], 0.f))
                                                      : (ushort_t)0;
          } else {
            if (col < 100) ((float*)out0)[(size_t)gRow * 128 + col] = v + bias0[col];
            else if (col < 200) {
              const int c = col - 100;
              const int pl = (c >= 64);
              ((u8*)out1)[pl * pstride + (size_t)gRow * 64 + (c - pl * 64)] = f2fp8(v);
            }
          }
        }
  }
}

// ---------------- fused conversion + weight packing ----------------
__global__ void pack_cvt(const float* __restrict__ x, ushort_t* __restrict__ xb,
                         u8* __restrict__ xf8, int n4, int M,
                         const float* __restrict__ W1, const float* __restrict__ W2,
                         const float* __restrict__ l1W, const float* __restrict__ l2W,
                         ushort_t* __restrict__ W1t, ushort_t* __restrict__ W2t,
                         ushort_t* __restrict__ Wlt) {
  const int i = blockIdx.x * 256 + threadIdx.x;
  if (i < n4) {
    const float4 v = ((const float4*)x)[i];
    ushort4 o; o.x = f2bf(v.x); o.y = f2bf(v.y); o.z = f2bf(v.z); o.w = f2bf(v.w);
    ((ushort4*)xb)[i] = o;
    int p = 0;
    p = __builtin_amdgcn_cvt_pk_fp8_f32(v.x, v.y, p, false);
    p = __builtin_amdgcn_cvt_pk_fp8_f32(v.z, v.w, p, true);
    const int row = i >> 5, g = i & 31;
    const int col = g * 4;
    const int pl = col >> 6, off = col & 63;
    *(unsigned*)(xf8 + (size_t)pl * M * 64 + (size_t)row * 64 + off) = (unsigned)p;
    return;
  }
  const int j = i - n4;
  if (j < 81920) {                       // W1t [320][256]
    const int n = j >> 8, k = j & 255;
    float v = 0.f;
    if (n < 300) v = (k < 128) ? W1[k * 300 + n] : W1[38400 + (k - 128) * 300 + n];
    W1t[j] = f2bf(v);
  } else if (j < 153600) {               // W2t [224][320]
    const int jj = j - 81920;
    const int n = jj / 320, k = jj - n * 320;
    float v = 0.f;
    if (n < 200 && k < 300) v = W2[(n < 100 ? 0 : 30000) + k * 100 + (n % 100)];
    W2t[jj] = f2bf(v);
  } else if (j < 182272) {               // Wlt [224][128]
    const int jj = j - 153600;
    const int n = jj >> 7, k = jj & 127;
    float v = 0.f;
    if (n < 100) v = l1W[n * 128 + k];
    else if (n < 200) v = l2W[(n - 100) * 128 + k];
    Wlt[jj] = f2bf(v);
  }
}

// ---------------- histogram + rank (unchanged R7) ----------------
__global__ __launch_bounds__(256) void hist2(
    const int* __restrict__ src, const int* __restrict__ dst, int E, int M,
    unsigned* __restrict__ partS, unsigned* __restrict__ partD,
    ushort_t* __restrict__ rank)
{
  __shared__ unsigned hist[HW];
  const int b = blockIdx.x;
  const int cs = (E + NB_H - 1) / NB_H;
  const int e0 = b * cs;
  const int e1 = (e0 + cs < E) ? e0 + cs : E;
  for (int isD = 0; isD < 2; ++isD) {
    const int* keys = isD ? dst : src;
    unsigned* part = isD ? partD : partS;
    for (int r = 0; r < 2; ++r) {
      const int klo = r * 2 * HW;
      for (int i = threadIdx.x; i < HW; i += 256) hist[i] = 0;
      __syncthreads();
      for (int e = e0 + threadIdx.x; e < e1; e += 256) {
        const int k = keys[e] - klo;
        if ((unsigned)k < (unsigned)(2 * HW)) {
          const unsigned old = atomicAdd(&hist[k >> 1], (k & 1) ? 0x10000u : 1u);
          if (isD) rank[e] = (ushort_t)((old >> ((k & 1) * 16)) & 0xffffu);
        }
      }
      __syncthreads();
      for (int i = threadIdx.x; i < HW; i += 256)
        part[(size_t)b * PW + r * HW + i] = hist[i];
      __syncthreads();
    }
  }
}

// ---------------- reduce_base2 (unchanged R9)
__global__ __launch_bounds__(256) void reduce_base2(
    const unsigned* __restrict__ partS, unsigned* __restrict__ partD,
    float* __restrict__ dinv, int* __restrict__ cnt, int M)
{
  const int t = blockIdx.x * 256 + threadIdx.x;
  if (t < PW) {
    const int i = t;
    unsigned ssum = 0;
    for (int b = 0; b < NB_H; b += 8) {
      unsigned v[8];
#pragma unroll
      for (int q = 0; q < 8; ++q) v[q] = partS[(size_t)(b + q) * PW + i];
#pragma unroll
      for (int q = 0; q < 8; ++q) ssum += v[q];
    }
    const int k = 2 * i;
    const unsigned s0 = ssum & 0xffffu, s1 = ssum >> 16;
    if (k < M) dinv[k] = s0 ? 1.f / sqrtf((float)s0) : 0.f;
    if (k + 1 < M) dinv[k + 1] = s1 ? 1.f / sqrtf((float)s1) : 0.f;
  } else if (t < 2 * PW) {
    const int i = t - PW;
    unsigned run = 0;
    for (int b = 0; b < NB_H; b += 8) {
      unsigned v[8], pre[8];
#pragma unroll
      for (int q = 0; q < 8; ++q) v[q] = partD[(size_t)(b + q) * PW + i];
#pragma unroll
      for (int q = 0; q < 8; ++q) { pre[q] = run; run += v[q]; }
#pragma unroll
      for (int q = 0; q < 8; ++q) partD[(size_t)(b + q) * PW + i] = pre[q];
    }
    const int k = 2 * i;
    if (k < M) cnt[k] = (int)(run & 0xffffu);
    if (k + 1 < M) cnt[k + 1] = (int)(run >> 16);
  }
}

// ---------------- scan (unchanged)
__global__ void scan_local(const int* __restrict__ cnt, int* __restrict__ ptr,
                           int* __restrict__ bsum, int n)
{
  __shared__ int tmp[256];
  const int i = blockIdx.x * 256 + threadIdx.x;
  const int v = (i < n) ? cnt[i] : 0;
  tmp[threadIdx.x] = v;
  __syncthreads();
  for (int off = 1; off < 256; off <<= 1) {
    const int t = (threadIdx.x >= off) ? tmp[threadIdx.x - off] : 0;
    __syncthreads();
    tmp[threadIdx.x] += t;
    __syncthreads();
  }
  if (i < n) ptr[i] = tmp[threadIdx.x] - v;
  if (threadIdx.x == 255) bsum[blockIdx.x] = tmp[255];
}
__global__ void scan_bsum(int* __restrict__ bsum, int nb, float* __restrict__ accs) {
  __shared__ int tmp[256];
  if (threadIdx.x < 2) accs[threadIdx.x] = 0.f;
  const int v = (threadIdx.x < nb) ? bsum[threadIdx.x] : 0;
  tmp[threadIdx.x] = v;
  __syncthreads();
  for (int off = 1; off < 256; off <<= 1) {
    const int t = (threadIdx.x >= off) ? tmp[threadIdx.x - off] : 0;
    __syncthreads();
    tmp[threadIdx.x] += t;
    __syncthreads();
  }
  if (threadIdx.x < nb) bsum[threadIdx.x] = tmp[threadIdx.x] - v;
}
__global__ void scan_add(int* __restrict__ ptr, const int* __restrict__ bsum, int n, int E) {
  const int i = blockIdx.x * 256 + threadIdx.x;
  if (i < n) ptr[i] += bsum[blockIdx.x];
  if (i == 0) ptr[n] = E;
}

// ---------------- atomic-free fill
__global__ void fill_csr2(const int* __restrict__ src, const int* __restrict__ dst,
                          const float* __restrict__ dinv, const int* __restrict__ ptr,
                          const unsigned* __restrict__ base32,
                          const ushort_t* __restrict__ rank,
                          int2* __restrict__ csr, int E)
{
  const int e = blockIdx.x * 256 + threadIdx.x;
  if (e >= E) return;
  const int cs = (E + NB_H - 1) / NB_H;
  const int b = e / cs;
  const int s = src[e], d = dst[e];
  const unsigned bv = base32[(size_t)b * PW + (d >> 1)];
  const int base = (int)((bv >> ((d & 1) * 16)) & 0xffffu);
  const int pos = ptr[d] + base + (int)rank[e];
  const float w = -dinv[s] * dinv[d];
  csr[pos] = make_int2(s, __float_as_int(w));
}

// fp8 decode+accumulate: 16 fp8 (uint4) scaled by ww into a[0..15]
#define ACCV(u, ww) { f32x2 t; \
  t = cvt2lo(u.x); a[0]  = fmaf(ww, t.x, a[0]);  a[1]  = fmaf(ww, t.y, a[1]);  \
  t = cvt2hi(u.x); a[2]  = fmaf(ww, t.x, a[2]);  a[3]  = fmaf(ww, t.y, a[3]);  \
  t = cvt2lo(u.y); a[4]  = fmaf(ww, t.x, a[4]);  a[5]  = fmaf(ww, t.y, a[5]);  \
  t = cvt2hi(u.y); a[6]  = fmaf(ww, t.x, a[6]);  a[7]  = fmaf(ww, t.y, a[7]);  \
  t = cvt2lo(u.z); a[8]  = fmaf(ww, t.x, a[8]);  a[9]  = fmaf(ww, t.y, a[9]);  \
  t = cvt2hi(u.z); a[10] = fmaf(ww, t.x, a[10]); a[11] = fmaf(ww, t.y, a[11]); \
  t = cvt2lo(u.w); a[12] = fmaf(ww, t.x, a[12]); a[13] = fmaf(ww, t.y, a[13]); \
  t = cvt2hi(u.w); a[14] = fmaf(ww, t.x, a[14]); a[15] = fmaf(ww, t.y, a[15]); }

// ---------------- gather128 plane pass: 4-lane slots x 16B = 64B plane row
template<int PLANE>
__global__ __launch_bounds__(256) void gather128p(
    const u8* __restrict__ xp, ushort_t* __restrict__ txb,
    const int* __restrict__ ptr, const int2* __restrict__ csr, int M)
{
  const int node = (blockIdx.x * 256 + threadIdx.x) >> 2;
  const int sub  = threadIdx.x & 3;
  if (node >= M) return;
  const int beg = ptr[node], end = ptr[node + 1];
  float a[16] = {};
  int p = beg;
  for (; p + 8 <= end; p += 8) {
    int2 e[8];
#pragma unroll
    for (int q = 0; q < 8; ++q) e[q] = csr[p + q];
    uint4 v[8];
#pragma unroll
    for (int q = 0; q < 8; ++q)
      v[q] = *(const uint4*)(xp + (size_t)e[q].x * 64 + sub * 16);
#pragma unroll
    for (int q = 0; q < 8; ++q) { const float wq = __int_as_float(e[q].y); ACCV(v[q], wq) }
  }
  for (; p < end; ++p) {
    const int2 eq = csr[p]; const float wq = __int_as_float(eq.y);
    const uint4 v = *(const uint4*)(xp + (size_t)eq.x * 64 + sub * 16);
    ACCV(v, wq)
  }
  uint4 o1, o2;
  o1.x = (unsigned)f2bf(a[0])  | ((unsigned)f2bf(a[1])  << 16);
  o1.y = (unsigned)f2bf(a[2])  | ((unsigned)f2bf(a[3])  << 16);
  o1.z = (unsigned)f2bf(a[4])  | ((unsigned)f2bf(a[5])  << 16);
  o1.w = (unsigned)f2bf(a[6])  | ((unsigned)f2bf(a[7])  << 16);
  o2.x = (unsigned)f2bf(a[8])  | ((unsigned)f2bf(a[9])  << 16);
  o2.y = (unsigned)f2bf(a[10]) | ((unsigned)f2bf(a[11]) << 16);
  o2.z = (unsigned)f2bf(a[12]) | ((unsigned)f2bf(a[13]) << 16);
  o2.w = (unsigned)f2bf(a[14]) | ((unsigned)f2bf(a[15]) << 16);
  ushort_t* dstp = txb + (size_t)node * 128 + PLANE * 64 + sub * 16;
  *(uint4*)dstp = o1;
  *(uint4*)(dstp + 8) = o2;
}

// ---------------- gather100 + x1 plane pass (PLANE1 cols>=100 garbage -> dead Ar cols)
template<int PLANE>
__global__ __launch_bounds__(256) void gather100p_x1(
    const u8* __restrict__ Bp, float* __restrict__ Ar,
    const int* __restrict__ ptr, const int2* __restrict__ csr, int M)
{
  const int node = (blockIdx.x * 256 + threadIdx.x) >> 2;
  const int sub  = threadIdx.x & 3;
  if (node >= M) return;
  const int beg = ptr[node], end = ptr[node + 1];
  float a[16] = {};
  int p = beg;
  for (; p + 8 <= end; p += 8) {
    int2 e[8];
#pragma unroll
    for (int q = 0; q < 8; ++q) e[q] = csr[p + q];
    uint4 v[8];
#pragma unroll
    for (int q = 0; q < 8; ++q)
      v[q] = *(const uint4*)(Bp + (size_t)e[q].x * 64 + sub * 16);
#pragma unroll
    for (int q = 0; q < 8; ++q) { const float wq = __int_as_float(e[q].y); ACCV(v[q], wq) }
  }
  for (; p < end; ++p) {
    const int2 eq = csr[p]; const float wq = __int_as_float(eq.y);
    const uint4 v = *(const uint4*)(Bp + (size_t)eq.x * 64 + sub * 16);
    ACCV(v, wq)
  }
  float* dstp = Ar + (size_t)node * 128 + PLANE * 64 + sub * 16;
#pragma unroll
  for (int q = 0; q < 4; ++q) {
    float4 b = *(const float4*)(dstp + q * 4);
    b.x = fmaxf(b.x + a[q * 4 + 0], 0.f);
    b.y = fmaxf(b.y + a[q * 4 + 1], 0.f);
    b.z = fmaxf(b.z + a[q * 4 + 2], 0.f);
    b.w = fmaxf(b.w + a[q * 4 + 3], 0.f);
    *(float4*)(dstp + q * 4) = b;
  }
}
#undef ACCV

#define DOTV(uu, vv, s) { f32x2 p_, q_; \
  p_ = cvt2lo(uu.x); q_ = cvt2lo(vv.x); s = fmaf(p_.x, q_.x, s); s = fmaf(p_.y, q_.y, s); \
  p_ = cvt2hi(uu.x); q_ = cvt2hi(vv.x); s = fmaf(p_.x, q_.x, s); s = fmaf(p_.y, q_.y, s); \
  p_ = cvt2lo(uu.y); q_ = cvt2lo(vv.y); s = fmaf(p_.x, q_.x, s); s = fmaf(p_.y, q_.y, s); \
  p_ = cvt2hi(uu.y); q_ = cvt2hi(vv.y); s = fmaf(p_.x, q_.x, s); s = fmaf(p_.y, q_.y, s); \
  p_ = cvt2lo(uu.z); q_ = cvt2lo(vv.z); s = fmaf(p_.x, q_.x, s); s = fmaf(p_.y, q_.y, s); \
  p_ = cvt2hi(uu.z); q_ = cvt2hi(vv.z); s = fmaf(p_.x, q_.x, s); s = fmaf(p_.y, q_.y, s); \
  p_ = cvt2lo(uu.w); q_ = cvt2lo(vv.w); s = fmaf(p_.x, q_.x, s); s = fmaf(p_.y, q_.y, s); \
  p_ = cvt2hi(uu.w); q_ = cvt2hi(vv.w); s = fmaf(p_.x, q_.x, s); s = fmaf(p_.y, q_.y, s); }

// ---------------- loss pass0: plane0 partial dots -> sp[2P]. 4-lane slots.
__global__ __launch_bounds__(256) void loss_p0(
    const u8* __restrict__ zp, const int* __restrict__ ep,
    const int* __restrict__ en, int P, float* __restrict__ sp)
{
  const int tid = threadIdx.x;
  const int sub = tid & 3;
  const int slot0 = blockIdx.x * 64 + (tid >> 2);
  const int step = gridDim.x * 64;
  int g = slot0;
  for (; g + 3 * step < 2 * P; g += 4 * step) {
    int na[4], nb[4];
#pragma unroll
    for (int q = 0; q < 4; ++q) {
      const int gq = g + q * step;
      const int neg = (gq >= P);
      const int p = neg ? gq - P : gq;
      const int* ia = neg ? en : ep;
      na[q] = ia[p]; nb[q] = ia[P + p];
    }
    uint4 ra[4], rb[4];
#pragma unroll
    for (int q = 0; q < 4; ++q) {
      ra[q] = *(const uint4*)(zp + (size_t)na[q] * 64 + sub * 16);
      rb[q] = *(const uint4*)(zp + (size_t)nb[q] * 64 + sub * 16);
    }
    float s[4] = {0.f, 0.f, 0.f, 0.f};
#pragma unroll
    for (int q = 0; q < 4; ++q) DOTV(ra[q], rb[q], s[q])
#pragma unroll
    for (int off = 2; off; off >>= 1)
#pragma unroll
      for (int q = 0; q < 4; ++q) s[q] += __shfl_down(s[q], off, 4);
    if (sub == 0)
#pragma unroll
      for (int q = 0; q < 4; ++q) sp[g + q * step] = s[q];
  }
  for (; g < 2 * P; g += step) {
    const int neg = (g >= P);
    const int p = neg ? g - P : g;
    const int* ia = neg ? en : ep;
    const int na = ia[p], nb = ia[P + p];
    const uint4 ra = *(const uint4*)(zp + (size_t)na * 64 + sub * 16);
    const uint4 rb = *(const uint4*)(zp + (size_t)nb * 64 + sub * 16);
    float s = 0.f;
    DOTV(ra, rb, s)
#pragma unroll
    for (int off = 2; off; off >>= 1) s += __shfl_down(s, off, 4);
    if (sub == 0) sp[g] = s;
  }
}

// ---------------- loss pass1: plane1 dots (cols 64-99 valid; mask garbage on
// BOTH operands before decode) + sp + sigmoid/log + reduce.
__global__ __launch_bounds__(256) void loss_p1(
    const u8* __restrict__ zp1, const int* __restrict__ ep,
    const int* __restrict__ en, int P, const float* __restrict__ sp,
    float* __restrict__ acc)
{
  __shared__ float red[8];
  const int tid = threadIdx.x;
  const int lane = tid & 63, wib = tid >> 6;
  const int sub = tid & 3;
  const int slot0 = blockIdx.x * 64 + (tid >> 2);
  const int step = gridDim.x * 64;
  float tp = 0.f, tn = 0.f;
  for (int g = slot0; g < 2 * P; g += step) {
    const int neg = (g >= P);
    const int p = neg ? g - P : g;
    const int* ia = neg ? en : ep;
    const int na = ia[p], nb = ia[P + p];
    float s = 0.f;
    if (sub < 3) {   // bytes [0,36) valid: sub0-1 full, sub2 keeps .x only
      uint4 ra = *(const uint4*)(zp1 + (size_t)na * 64 + sub * 16);
      uint4 rb = *(const uint4*)(zp1 + (size_t)nb * 64 + sub * 16);
      if (sub == 2) { ra.y = ra.z = ra.w = 0u; rb.y = rb.z = rb.w = 0u; }
      DOTV(ra, rb, s)
    }
#pragma unroll
    for (int off = 2; off; off >>= 1) s += __shfl_down(s, off, 4);
    if (sub == 0) {
      const float st = s + sp[g];
      const float sig = 1.f / (1.f + expf(-st));
      if (neg) tn += logf(1.f - sig + 1e-15f); else tp += logf(sig + 1e-15f);
    }
  }
  tp += __shfl_down(tp, 32, 64); tn += __shfl_down(tn, 32, 64);
  tp += __shfl_down(tp, 16, 64); tn += __shfl_down(tn, 16, 64);
  tp += __shfl_down(tp, 8, 64);  tn += __shfl_down(tn, 8, 64);
  tp += __shfl_down(tp, 4, 64);  tn += __shfl_down(tn, 4, 64);
  if (lane == 0) { red[wib] = tp; red[4 + wib] = tn; }
  __syncthreads();
  if (tid == 0) {
    atomicAdd(acc + 0, red[0] + red[1] + red[2] + red[3]);
    atomicAdd(acc + 1, red[4] + red[5] + red[6] + red[7]);
  }
}
#undef DOTV

// ---------------- fused gather2 + final
__global__ void gather2_final(
    const float* __restrict__ t1, const float* __restrict__ t0,
    const int* __restrict__ ptr, const int2* __restrict__ csr,
    const float* __restrict__ accs,
    const float* __restrict__ c1, const float* __restrict__ c2,
    float* __restrict__ out, int M, float invP)
{
  const int i = blockIdx.x * blockDim.x + threadIdx.x;
  if (i < M) {
    float a0 = 0.f, a1 = 0.f;
    const int beg = ptr[i], end = ptr[i + 1];
    int p = beg;
    for (; p + 4 <= end; p += 4) {
      const int2 e0 = csr[p], e1 = csr[p + 1], e2 = csr[p + 2], e3 = csr[p + 3];
      const float w0 = __int_as_float(e0.y), w1 = __int_as_float(e1.y);
      const float w2 = __int_as_float(e2.y), w3 = __int_as_float(e3.y);
      const float2 v0 = *(const float2*)(t1 + (size_t)e0.x * 2);
      const float2 v1 = *(const float2*)(t1 + (size_t)e1.x * 2);
      const float2 v2 = *(const float2*)(t1 + (size_t)e2.x * 2);
      const float2 v3 = *(const float2*)(t1 + (size_t)e3.x * 2);
      a0 = fmaf(w0, v0.x, a0); a1 = fmaf(w0, v0.y, a1);
      a0 = fmaf(w1, v1.x, a0); a1 = fmaf(w1, v1.y, a1);
      a0 = fmaf(w2, v2.x, a0); a1 = fmaf(w2, v2.y, a1);
      a0 = fmaf(w3, v3.x, a0); a1 = fmaf(w3, v3.y, a1);
    }
    for (; p < end; ++p) {
      const int2 eq = csr[p]; const float wq = __int_as_float(eq.y);
      const float2 v = *(const float2*)(t1 + (size_t)eq.x * 2);
      a0 = fmaf(wq, v.x, a0); a1 = fmaf(wq, v.y, a1);
    }
    const float2 base = *(const float2*)(t0 + (size_t)i * 2);
    *(float2*)(out + (size_t)i * 2) = make_float2(base.x + a0, base.y + a1);
  }
  if (i == 0) {
    out[2 * M + 0] = -(accs[0] + accs[1]) * invP;
    out[2 * M + 1] = c1[0];
    out[2 * M + 2] = c2[0];
  }
}

extern "C" void kernel_launch(void* const* d_in, const int* in_sizes, int n_in,
                              void* d_out, int out_size, void* d_ws, size_t ws_size,
                              hipStream_t stream)
{
  const float* x   = (const float*)d_in[0];
  const int*   ei  = (const int*)d_in[1];
  const int*   ep  = (const int*)d_in[2];
  const int*   en  = (const int*)d_in[3];
  const float* W1  = (const float*)d_in[4];
  const float* b1  = (const float*)d_in[5];
  const float* W2  = (const float*)d_in[6];
  const float* b2  = (const float*)d_in[7];
  const float* W3  = (const float*)d_in[8];
  const float* b3  = (const float*)d_in[9];
  const float* l1W = (const float*)d_in[10];
  const float* l1b = (const float*)d_in[11];
  const float* l2W = (const float*)d_in[12];
  const float* l2b = (const float*)d_in[13];
  const float* c1  = (const float*)d_in[14];
  const float* c2  = (const float*)d_in[15];
  float* out = (float*)d_out;

  const int M = in_sizes[0] / 128;  // 50000
  const int E = in_sizes[1] / 2;    // 800000
  const int P = in_sizes[2] / 2;    // 400000
  const int* src = ei;
  const int* dst = ei + E;
  const int nb_scan = (M + 255) / 256;

  float* ws = (float*)d_ws;
  size_t o = 0;
  float*    dinv = ws + o;            o += 50176;
  int*      cnt  = (int*)(ws + o);    o += (size_t)M;
  int*      ptr  = (int*)(ws + o);    o += (size_t)M + 8;
  int*      bsum = (int*)(ws + o);    o += 256;
  int2*     csr  = (int2*)(ws + o);   o += (size_t)E * 2;
  ushort_t* rank = (ushort_t*)(ws + o); o += (size_t)E / 2;
  ushort_t* xb   = (ushort_t*)(ws + o); o += (size_t)M * 64;   // bf16 [M][128]
  u8*       xf8  = (u8*)(ws + o);     o += (size_t)M * 32;     // fp8 2 planes [M][64]
  ushort_t* tx0b = (ushort_t*)(ws + o); o += (size_t)M * 64;   // bf16 [M][128]
  ushort_t* W1t  = (ushort_t*)(ws + o); o += 40960;
  ushort_t* W2t  = (ushort_t*)(ws + o); o += 35840;
  ushort_t* Wlt  = (ushort_t*)(ws + o); o += 14336;
  ushort_t* h    = (ushort_t*)(ws + o); o += (size_t)M * 160;  // bf16 [M][320], 32MB
  float*    Ar   = ws + o;            o += (size_t)M * 128;    // f32 stride128, 25.6MB
  u8*       Brh  = (u8*)(ws + o);     o += (size_t)M * 32;     // fp8 2 planes
  u8*       zf8  = (u8*)(ws + o);     o += (size_t)M * 32;     // fp8 2 planes
  float*    sp   = ws + o;            o += (size_t)2 * P;      // partial dots
  float*    t0   = ws + o;            o += (size_t)M * 2;
  float*    t1   = ws + o;            o += (size_t)M * 2;
  float*    accs = ws + o;            o += 8;
  unsigned* partS = (unsigned*)h;   // aliases, dead during CSR build
  unsigned* partD = (unsigned*)Ar;
  const size_t pstride = (size_t)M * 64;

  // packing + conversion
  const int n4 = M * 32;
  pack_cvt<<<(n4 + 182272 + 255) / 256, 256, 0, stream>>>(
      x, xb, xf8, n4, M, W1, W2, l1W, l2W, W1t, W2t, Wlt);

  // CSR build (no global atomics)
  hist2<<<NB_H, 256, 0, stream>>>(src, dst, E, M, partS, partD, rank);
  reduce_base2<<<(2 * PW + 255) / 256, 256, 0, stream>>>(partS, partD, dinv, cnt, M);
  scan_local<<<nb_scan, 256, 0, stream>>>(cnt, ptr, bsum, M);
  scan_bsum<<<1, 256, 0, stream>>>(bsum, nb_scan, accs);
  scan_add<<<nb_scan, 256, 0, stream>>>(ptr, bsum, M, E);
  fill_csr2<<<(E + 255) / 256, 256, 0, stream>>>(src, dst, dinv, ptr, partD, rank, csr, E);

  const int gB = (M + 63) / 64;
  const int gP4 = (M * 4 + 255) / 256;

  // conv1: two plane passes, then GEMM
  gather128p<0><<<gP4, 256, 0, stream>>>(xf8, tx0b, ptr, csr, M);
  gather128p<1><<<gP4, 256, 0, stream>>>(xf8 + pstride, tx0b, ptr, csr, M);
  gemm_mfma<0, 320, 256><<<gB, 256, 0, stream>>>(
      xb, tx0b, W1t, b1, nullptr, nullptr, nullptr, nullptr, h, nullptr, nullptr, nullptr, M);

  // conv2
  gemm_mfma<1, 224, 320><<<gB, 256, 0, stream>>>(
      h, nullptr, W2t, b2, nullptr, nullptr, nullptr, nullptr, Ar, Brh, nullptr, nullptr, M);
  gather100p_x1<0><<<gP4, 256, 0, stream>>>(Brh, Ar, ptr, csr, M);
  gather100p_x1<1><<<gP4, 256, 0, stream>>>(Brh + pstride, Ar, ptr, csr, M);

  // lins + fused w3
  gemm_mfma<2, 224, 128><<<gB, 256, 0, stream>>>(
      xb, nullptr, Wlt, l1b, l2b, Ar /*x1*/, W3, b3, nullptr, zf8, t0, t1, M);

  // loss: two plane passes
  loss_p0<<<2048, 256, 0, stream>>>(zf8, ep, en, P, sp);
  loss_p1<<<2048, 256, 0, stream>>>(zf8 + pstride, ep, en, P, sp, accs);

  // conv3 propagation + final
  gather2_final<<<(M + 255) / 256, 256, 0, stream>>>(t1, t0, ptr, csr,
                                                     accs, c1, c2, out, M, 1.0f / (float)P);
}

// Round 13
// 496.101 us; speedup vs baseline: 1.0125x; 1.0125x over previous
//
#include <hip/hip_runtime.h>
#include <math.h>

// MTGCN R11: R10 + (1) loss_p1 regains 4-way pair ILP (R10 regression root cause:
// plane pass 1 was latency-bound with no ILP); (2) h stored as fp8 [M][320]
// (VAR0 writes fp8, VAR1 A-stage converts fp8->bf16 in-register) halving h traffic.
// Plane-split fp8 (2x64B planes, L2-resident), atomic-free CSR, bf16 MFMA GEMMs.

typedef unsigned short ushort_t;
typedef unsigned char u8;
typedef __attribute__((ext_vector_type(8))) __bf16 bf16x8;
typedef __attribute__((ext_vector_type(8))) short s16x8;
typedef __attribute__((ext_vector_type(4))) float f32x4;
typedef __attribute__((ext_vector_type(2))) float f32x2;

#define NB_H 256
#define HW 12500
#define PW 25000

__device__ __forceinline__ f32x4 mfma16x16x32(s16x8 a, s16x8 b, f32x4 c) {
  return __builtin_amdgcn_mfma_f32_16x16x32_bf16(
      __builtin_bit_cast(bf16x8, a), __builtin_bit_cast(bf16x8, b), c, 0, 0, 0);
}
__device__ __forceinline__ ushort_t f2bf(float f) {
  union { float f; unsigned u; } c; c.f = f;
  unsigned r = (c.u + 0x7FFFu + ((c.u >> 16) & 1u)) >> 16;
  return (ushort_t)r;
}
__device__ __forceinline__ f32x2 cvt2lo(unsigned u) {
  return __builtin_amdgcn_cvt_pk_f32_fp8((int)u, false);
}
__device__ __forceinline__ f32x2 cvt2hi(unsigned u) {
  return __builtin_amdgcn_cvt_pk_f32_fp8((int)u, true);
}
__device__ __forceinline__ u8 f2fp8(float f) {
  return (u8)(__builtin_amdgcn_cvt_pk_fp8_f32(f, 0.f, 0, false) & 0xff);
}

// =======================================================================
// MFMA GEMM. VAR0: A=[xb|tx0b] bf16 -> h fp8 [M][320] (relu+b1).
// VAR1: A=h fp8 [M][320] (convert->bf16 during staging) -> Ar f32 / Brh fp8 planes.
// VAR2: A=xb bf16 -> zf8 planes + t0/t1 via w3 reduce.
// =======================================================================
template<int VAR, int NT, int KTOT>
__global__ __launch_bounds__(256) void gemm_mfma(
    const ushort_t* __restrict__ A0, const ushort_t* __restrict__ A1,
    const ushort_t* __restrict__ Wt,
    const float* __restrict__ bias0, const float* __restrict__ bias1,
    const float* __restrict__ x1,
    const float* __restrict__ W3c, const float* __restrict__ b3c,
    void* __restrict__ out0, void* __restrict__ out1,
    float* __restrict__ t0g, float* __restrict__ t1g, int M)
{
  constexpr int NF = NT / 32;
  __shared__ __align__(16) ushort_t As[64 * 40];
  __shared__ __align__(16) ushort_t Bs[NT * 40];
  __shared__ float w3s[400];
  const int tid  = threadIdx.x;
  const int lane = tid & 63, w = tid >> 6;
  const int m0 = blockIdx.x * 64;
  const int wm = (w & 1) * 32, wn = (w >> 1) * (NT / 2);
  const size_t pstride = (size_t)M * 64;   // fp8 plane stride (bytes)
  if (VAR == 2) { for (int i = tid; i < 400; i += 256) w3s[i] = W3c[i]; }
  f32x4 acc[2][NF];
#pragma unroll
  for (int i = 0; i < 2; ++i)
#pragma unroll
    for (int j = 0; j < NF; ++j) acc[i][j] = (f32x4){0.f, 0.f, 0.f, 0.f};

  for (int k0 = 0; k0 < KTOT; k0 += 32) {
    { // A stage
      const int r = tid >> 2, c8 = (tid & 3) * 8;
      const int gm = m0 + r;
      uint4 v = {0u, 0u, 0u, 0u};
      if (gm < M) {
        if (VAR == 1) {  // fp8 h: load 8 bytes, convert to 8 bf16
          const u8* s8 = (const u8*)A0 + (size_t)gm * 320 + k0 + c8;
          const uint2 r8 = *(const uint2*)s8;
          const f32x2 f0 = cvt2lo(r8.x), f1 = cvt2hi(r8.x);
          const f32x2 f2 = cvt2lo(r8.y), f3 = cvt2hi(r8.y);
          v.x = (unsigned)f2bf(f0.x) | ((unsigned)f2bf(f0.y) << 16);
          v.y = (unsigned)f2bf(f1.x) | ((unsigned)f2bf(f1.y) << 16);
          v.z = (unsigned)f2bf(f2.x) | ((unsigned)f2bf(f2.y) << 16);
          v.w = (unsigned)f2bf(f3.x) | ((unsigned)f2bf(f3.y) << 16);
        } else {
          const ushort_t* srcp;
          if (VAR == 0) srcp = (k0 < 128) ? A0 + (size_t)gm * 128 + k0 + c8
                                          : A1 + (size_t)gm * 128 + (k0 - 128) + c8;
          else srcp = A0 + (size_t)gm * 128 + k0 + c8;
          v = *(const uint4*)srcp;
        }
      }
      *(uint4*)&As[r * 40 + c8] = v;
    }
    { // B stage
      const int c8 = (tid & 3) * 8;
#pragma unroll
      for (int i = 0; i < (NT * 4 + 255) / 256; ++i) {
        const int r = (tid >> 2) + i * 64;
        if (r < NT)
          *(uint4*)&Bs[r * 40 + c8] = *(const uint4*)(Wt + (size_t)r * KTOT + k0 + c8);
      }
    }
    __syncthreads();
    s16x8 af[2], bfr[NF];
#pragma unroll
    for (int mi = 0; mi < 2; ++mi)
      af[mi] = *(const s16x8*)&As[(wm + mi * 16 + (lane & 15)) * 40 + (lane >> 4) * 8];
#pragma unroll
    for (int ni = 0; ni < NF; ++ni)
      bfr[ni] = *(const s16x8*)&Bs[(wn + ni * 16 + (lane & 15)) * 40 + (lane >> 4) * 8];
#pragma unroll
    for (int mi = 0; mi < 2; ++mi)
#pragma unroll
      for (int ni = 0; ni < NF; ++ni)
        acc[mi][ni] = mfma16x16x32(af[mi], bfr[ni], acc[mi][ni]);
    __syncthreads();
  }

  if (VAR == 2) {
#pragma unroll
    for (int mi = 0; mi < 2; ++mi)
#pragma unroll
      for (int r = 0; r < 4; ++r) {
        const int gRow = m0 + wm + mi * 16 + ((lane >> 4) << 2) + r;
        float p0 = 0.f, p1 = 0.f, p2 = 0.f, p3 = 0.f;
#pragma unroll
        for (int ni = 0; ni < NF; ++ni) {
          const int col = wn + ni * 16 + (lane & 15);
          const float v = acc[mi][ni][r];
          if (gRow < M) {
            if (col < 100) {
              const float x2v = x1[(size_t)gRow * 128 + col] + fmaxf(v + bias0[col], 0.f);
              p0 = fmaf(x2v, w3s[col * 2 + 0], p0);
              p1 = fmaf(x2v, w3s[col * 2 + 1], p1);
              p2 = fmaf(x2v, w3s[200 + col * 2 + 0], p2);
              p3 = fmaf(x2v, w3s[200 + col * 2 + 1], p3);
            } else if (col < 200) {
              const int c = col - 100;
              const int pl = (c >= 64);
              ((u8*)out1)[pl * pstride + (size_t)gRow * 64 + (c - pl * 64)] =
                  f2fp8(x1[(size_t)gRow * 128 + c] + fmaxf(v + bias1[c], 0.f));
            }
          }
        }
        if (wn == 0) {
#pragma unroll
          for (int off = 8; off; off >>= 1) {
            p0 += __shfl_down(p0, off, 16);
            p1 += __shfl_down(p1, off, 16);
            p2 += __shfl_down(p2, off, 16);
            p3 += __shfl_down(p3, off, 16);
          }
          if ((lane & 15) == 0 && gRow < M) {
            t0g[(size_t)gRow * 2 + 0] = p0 + b3c[0];
            t0g[(size_t)gRow * 2 + 1] = p1 + b3c[1];
            t1g[(size_t)gRow * 2 + 0] = p2;
            t1g[(size_t)gRow * 2 + 1] = p3;
          }
        }
      }
  } else {
#pragma unroll
    for (int mi = 0; mi < 2; ++mi)
#pragma unroll
      for (int ni = 0; ni < NF; ++ni)
#pragma unroll
        for (int r = 0; r < 4; ++r) {
          const int gRow = m0 + wm + mi * 16 + ((lane >> 4) << 2) + r;
          const int col  = wn + ni * 16 + (lane & 15);
          if (gRow >= M) continue;
          const float v = acc[mi][ni][r];
          if (VAR == 0) {
            ((u8*)out0)[(size_t)gRow * 320 + col] =
                (col < 300) ? f2fp8(fmaxf(v + bias0[col], 0.f)) : (u8)0;
          } else {
            if (col < 100) ((float*)out0)[(size_t)gRow * 128 + col] = v + bias0[col];
            else if (col < 200) {
              const int c = col - 100;
              const int pl = (c >= 64);
              ((u8*)out1)[pl * pstride + (size_t)gRow * 64 + (c - pl * 64)] = f2fp8(v);
            }
          }
        }
  }
}

// ---------------- fused conversion + weight packing ----------------
__global__ void pack_cvt(const float* __restrict__ x, ushort_t* __restrict__ xb,
                         u8* __restrict__ xf8, int n4, int M,
                         const float* __restrict__ W1, const float* __restrict__ W2,
                         const float* __restrict__ l1W, const float* __restrict__ l2W,
                         ushort_t* __restrict__ W1t, ushort_t* __restrict__ W2t,
                         ushort_t* __restrict__ Wlt) {
  const int i = blockIdx.x * 256 + threadIdx.x;
  if (i < n4) {
    const float4 v = ((const float4*)x)[i];
    ushort4 o; o.x = f2bf(v.x); o.y = f2bf(v.y); o.z = f2bf(v.z); o.w = f2bf(v.w);
    ((ushort4*)xb)[i] = o;
    int p = 0;
    p = __builtin_amdgcn_cvt_pk_fp8_f32(v.x, v.y, p, false);
    p = __builtin_amdgcn_cvt_pk_fp8_f32(v.z, v.w, p, true);
    const int row = i >> 5, g = i & 31;
    const int col = g * 4;
    const int pl = col >> 6, off = col & 63;
    *(unsigned*)(xf8 + (size_t)pl * M * 64 + (size_t)row * 64 + off) = (unsigned)p;
    return;
  }
  const int j = i - n4;
  if (j < 81920) {                       // W1t [320][256]
    const int n = j >> 8, k = j & 255;
    float v = 0.f;
    if (n < 300) v = (k < 128) ? W1[k * 300 + n] : W1[38400 + (k - 128) * 300 + n];
    W1t[j] = f2bf(v);
  } else if (j < 153600) {               // W2t [224][320]
    const int jj = j - 81920;
    const int n = jj / 320, k = jj - n * 320;
    float v = 0.f;
    if (n < 200 && k < 300) v = W2[(n < 100 ? 0 : 30000) + k * 100 + (n % 100)];
    W2t[jj] = f2bf(v);
  } else if (j < 182272) {               // Wlt [224][128]
    const int jj = j - 153600;
    const int n = jj >> 7, k = jj & 127;
    float v = 0.f;
    if (n < 100) v = l1W[n * 128 + k];
    else if (n < 200) v = l2W[(n - 100) * 128 + k];
    Wlt[jj] = f2bf(v);
  }
}

// ---------------- histogram + rank ----------------
__global__ __launch_bounds__(256) void hist2(
    const int* __restrict__ src, const int* __restrict__ dst, int E, int M,
    unsigned* __restrict__ partS, unsigned* __restrict__ partD,
    ushort_t* __restrict__ rank)
{
  __shared__ unsigned hist[HW];
  const int b = blockIdx.x;
  const int cs = (E + NB_H - 1) / NB_H;
  const int e0 = b * cs;
  const int e1 = (e0 + cs < E) ? e0 + cs : E;
  for (int isD = 0; isD < 2; ++isD) {
    const int* keys = isD ? dst : src;
    unsigned* part = isD ? partD : partS;
    for (int r = 0; r < 2; ++r) {
      const int klo = r * 2 * HW;
      for (int i = threadIdx.x; i < HW; i += 256) hist[i] = 0;
      __syncthreads();
      for (int e = e0 + threadIdx.x; e < e1; e += 256) {
        const int k = keys[e] - klo;
        if ((unsigned)k < (unsigned)(2 * HW)) {
          const unsigned old = atomicAdd(&hist[k >> 1], (k & 1) ? 0x10000u : 1u);
          if (isD) rank[e] = (ushort_t)((old >> ((k & 1) * 16)) & 0xffffu);
        }
      }
      __syncthreads();
      for (int i = threadIdx.x; i < HW; i += 256)
        part[(size_t)b * PW + r * HW + i] = hist[i];
      __syncthreads();
    }
  }
}

// ---------------- reduce_base2
__global__ __launch_bounds__(256) void reduce_base2(
    const unsigned* __restrict__ partS, unsigned* __restrict__ partD,
    float* __restrict__ dinv, int* __restrict__ cnt, int M)
{
  const int t = blockIdx.x * 256 + threadIdx.x;
  if (t < PW) {
    const int i = t;
    unsigned ssum = 0;
    for (int b = 0; b < NB_H; b += 8) {
      unsigned v[8];
#pragma unroll
      for (int q = 0; q < 8; ++q) v[q] = partS[(size_t)(b + q) * PW + i];
#pragma unroll
      for (int q = 0; q < 8; ++q) ssum += v[q];
    }
    const int k = 2 * i;
    const unsigned s0 = ssum & 0xffffu, s1 = ssum >> 16;
    if (k < M) dinv[k] = s0 ? 1.f / sqrtf((float)s0) : 0.f;
    if (k + 1 < M) dinv[k + 1] = s1 ? 1.f / sqrtf((float)s1) : 0.f;
  } else if (t < 2 * PW) {
    const int i = t - PW;
    unsigned run = 0;
    for (int b = 0; b < NB_H; b += 8) {
      unsigned v[8], pre[8];
#pragma unroll
      for (int q = 0; q < 8; ++q) v[q] = partD[(size_t)(b + q) * PW + i];
#pragma unroll
      for (int q = 0; q < 8; ++q) { pre[q] = run; run += v[q]; }
#pragma unroll
      for (int q = 0; q < 8; ++q) partD[(size_t)(b + q) * PW + i] = pre[q];
    }
    const int k = 2 * i;
    if (k < M) cnt[k] = (int)(run & 0xffffu);
    if (k + 1 < M) cnt[k + 1] = (int)(run >> 16);
  }
}

// ---------------- scan
__global__ void scan_local(const int* __restrict__ cnt, int* __restrict__ ptr,
                           int* __restrict__ bsum, int n)
{
  __shared__ int tmp[256];
  const int i = blockIdx.x * 256 + threadIdx.x;
  const int v = (i < n) ? cnt[i] : 0;
  tmp[threadIdx.x] = v;
  __syncthreads();
  for (int off = 1; off < 256; off <<= 1) {
    const int t = (threadIdx.x >= off) ? tmp[threadIdx.x - off] : 0;
    __syncthreads();
    tmp[threadIdx.x] += t;
    __syncthreads();
  }
  if (i < n) ptr[i] = tmp[threadIdx.x] - v;
  if (threadIdx.x == 255) bsum[blockIdx.x] = tmp[255];
}
__global__ void scan_bsum(int* __restrict__ bsum, int nb, float* __restrict__ accs) {
  __shared__ int tmp[256];
  if (threadIdx.x < 2) accs[threadIdx.x] = 0.f;
  const int v = (threadIdx.x < nb) ? bsum[threadIdx.x] : 0;
  tmp[threadIdx.x] = v;
  __syncthreads();
  for (int off = 1; off < 256; off <<= 1) {
    const int t = (threadIdx.x >= off) ? tmp[threadIdx.x - off] : 0;
    __syncthreads();
    tmp[threadIdx.x] += t;
    __syncthreads();
  }
  if (threadIdx.x < nb) bsum[threadIdx.x] = tmp[threadIdx.x] - v;
}
__global__ void scan_add(int* __restrict__ ptr, const int* __restrict__ bsum, int n, int E) {
  const int i = blockIdx.x * 256 + threadIdx.x;
  if (i < n) ptr[i] += bsum[blockIdx.x];
  if (i == 0) ptr[n] = E;
}

// ---------------- atomic-free fill
__global__ void fill_csr2(const int* __restrict__ src, const int* __restrict__ dst,
                          const float* __restrict__ dinv, const int* __restrict__ ptr,
                          const unsigned* __restrict__ base32,
                          const ushort_t* __restrict__ rank,
                          int2* __restrict__ csr, int E)
{
  const int e = blockIdx.x * 256 + threadIdx.x;
  if (e >= E) return;
  const int cs = (E + NB_H - 1) / NB_H;
  const int b = e / cs;
  const int s = src[e], d = dst[e];
  const unsigned bv = base32[(size_t)b * PW + (d >> 1)];
  const int base = (int)((bv >> ((d & 1) * 16)) & 0xffffu);
  const int pos = ptr[d] + base + (int)rank[e];
  const float w = -dinv[s] * dinv[d];
  csr[pos] = make_int2(s, __float_as_int(w));
}

#define ACCV(u, ww) { f32x2 t; \
  t = cvt2lo(u.x); a[0]  = fmaf(ww, t.x, a[0]);  a[1]  = fmaf(ww, t.y, a[1]);  \
  t = cvt2hi(u.x); a[2]  = fmaf(ww, t.x, a[2]);  a[3]  = fmaf(ww, t.y, a[3]);  \
  t = cvt2lo(u.y); a[4]  = fmaf(ww, t.x, a[4]);  a[5]  = fmaf(ww, t.y, a[5]);  \
  t = cvt2hi(u.y); a[6]  = fmaf(ww, t.x, a[6]);  a[7]  = fmaf(ww, t.y, a[7]);  \
  t = cvt2lo(u.z); a[8]  = fmaf(ww, t.x, a[8]);  a[9]  = fmaf(ww, t.y, a[9]);  \
  t = cvt2hi(u.z); a[10] = fmaf(ww, t.x, a[10]); a[11] = fmaf(ww, t.y, a[11]); \
  t = cvt2lo(u.w); a[12] = fmaf(ww, t.x, a[12]); a[13] = fmaf(ww, t.y, a[13]); \
  t = cvt2hi(u.w); a[14] = fmaf(ww, t.x, a[14]); a[15] = fmaf(ww, t.y, a[15]); }

// ---------------- gather128 plane pass
template<int PLANE>
__global__ __launch_bounds__(256) void gather128p(
    const u8* __restrict__ xp, ushort_t* __restrict__ txb,
    const int* __restrict__ ptr, const int2* __restrict__ csr, int M)
{
  const int node = (blockIdx.x * 256 + threadIdx.x) >> 2;
  const int sub  = threadIdx.x & 3;
  if (node >= M) return;
  const int beg = ptr[node], end = ptr[node + 1];
  float a[16] = {};
  int p = beg;
  for (; p + 8 <= end; p += 8) {
    int2 e[8];
#pragma unroll
    for (int q = 0; q < 8; ++q) e[q] = csr[p + q];
    uint4 v[8];
#pragma unroll
    for (int q = 0; q < 8; ++q)
      v[q] = *(const uint4*)(xp + (size_t)e[q].x * 64 + sub * 16);
#pragma unroll
    for (int q = 0; q < 8; ++q) { const float wq = __int_as_float(e[q].y); ACCV(v[q], wq) }
  }
  for (; p < end; ++p) {
    const int2 eq = csr[p]; const float wq = __int_as_float(eq.y);
    const uint4 v = *(const uint4*)(xp + (size_t)eq.x * 64 + sub * 16);
    ACCV(v, wq)
  }
  uint4 o1, o2;
  o1.x = (unsigned)f2bf(a[0])  | ((unsigned)f2bf(a[1])  << 16);
  o1.y = (unsigned)f2bf(a[2])  | ((unsigned)f2bf(a[3])  << 16);
  o1.z = (unsigned)f2bf(a[4])  | ((unsigned)f2bf(a[5])  << 16);
  o1.w = (unsigned)f2bf(a[6])  | ((unsigned)f2bf(a[7])  << 16);
  o2.x = (unsigned)f2bf(a[8])  | ((unsigned)f2bf(a[9])  << 16);
  o2.y = (unsigned)f2bf(a[10]) | ((unsigned)f2bf(a[11]) << 16);
  o2.z = (unsigned)f2bf(a[12]) | ((unsigned)f2bf(a[13]) << 16);
  o2.w = (unsigned)f2bf(a[14]) | ((unsigned)f2bf(a[15]) << 16);
  ushort_t* dstp = txb + (size_t)node * 128 + PLANE * 64 + sub * 16;
  *(uint4*)dstp = o1;
  *(uint4*)(dstp + 8) = o2;
}

// ---------------- gather100 + x1 plane pass
template<int PLANE>
__global__ __launch_bounds__(256) void gather100p_x1(
    const u8* __restrict__ Bp, float* __restrict__ Ar,
    const int* __restrict__ ptr, const int2* __restrict__ csr, int M)
{
  const int node = (blockIdx.x * 256 + threadIdx.x) >> 2;
  const int sub  = threadIdx.x & 3;
  if (node >= M) return;
  const int beg = ptr[node], end = ptr[node + 1];
  float a[16] = {};
  int p = beg;
  for (; p + 8 <= end; p += 8) {
    int2 e[8];
#pragma unroll
    for (int q = 0; q < 8; ++q) e[q] = csr[p + q];
    uint4 v[8];
#pragma unroll
    for (int q = 0; q < 8; ++q)
      v[q] = *(const uint4*)(Bp + (size_t)e[q].x * 64 + sub * 16);
#pragma unroll
    for (int q = 0; q < 8; ++q) { const float wq = __int_as_float(e[q].y); ACCV(v[q], wq) }
  }
  for (; p < end; ++p) {
    const int2 eq = csr[p]; const float wq = __int_as_float(eq.y);
    const uint4 v = *(const uint4*)(Bp + (size_t)eq.x * 64 + sub * 16);
    ACCV(v, wq)
  }
  float* dstp = Ar + (size_t)node * 128 + PLANE * 64 + sub * 16;
#pragma unroll
  for (int q = 0; q < 4; ++q) {
    float4 b = *(const float4*)(dstp + q * 4);
    b.x = fmaxf(b.x + a[q * 4 + 0], 0.f);
    b.y = fmaxf(b.y + a[q * 4 + 1], 0.f);
    b.z = fmaxf(b.z + a[q * 4 + 2], 0.f);
    b.w = fmaxf(b.w + a[q * 4 + 3], 0.f);
    *(float4*)(dstp + q * 4) = b;
  }
}
#undef ACCV

#define DOTV(uu, vv, s) { f32x2 p_, q_; \
  p_ = cvt2lo(uu.x); q_ = cvt2lo(vv.x); s = fmaf(p_.x, q_.x, s); s = fmaf(p_.y, q_.y, s); \
  p_ = cvt2hi(uu.x); q_ = cvt2hi(vv.x); s = fmaf(p_.x, q_.x, s); s = fmaf(p_.y, q_.y, s); \
  p_ = cvt2lo(uu.y); q_ = cvt2lo(vv.y); s = fmaf(p_.x, q_.x, s); s = fmaf(p_.y, q_.y, s); \
  p_ = cvt2hi(uu.y); q_ = cvt2hi(vv.y); s = fmaf(p_.x, q_.x, s); s = fmaf(p_.y, q_.y, s); \
  p_ = cvt2lo(uu.z); q_ = cvt2lo(vv.z); s = fmaf(p_.x, q_.x, s); s = fmaf(p_.y, q_.y, s); \
  p_ = cvt2hi(uu.z); q_ = cvt2hi(vv.z); s = fmaf(p_.x, q_.x, s); s = fmaf(p_.y, q_.y, s); \
  p_ = cvt2lo(uu.w); q_ = cvt2lo(vv.w); s = fmaf(p_.x, q_.x, s); s = fmaf(p_.y, q_.y, s); \
  p_ = cvt2hi(uu.w); q_ = cvt2hi(vv.w); s = fmaf(p_.x, q_.x, s); s = fmaf(p_.y, q_.y, s); }

// ---------------- loss pass0: plane0 partial dots -> sp[2P] (4-way ILP)
__global__ __launch_bounds__(256) void loss_p0(
    const u8* __restrict__ zp, const int* __restrict__ ep,
    const int* __restrict__ en, int P, float* __restrict__ sp)
{
  const int tid = threadIdx.x;
  const int sub = tid & 3;
  const int slot0 = blockIdx.x * 64 + (tid >> 2);
  const int step = gridDim.x * 64;
  int g = slot0;
  for (; g + 3 * step < 2 * P; g += 4 * step) {
    int na[4], nb[4];
#pragma unroll
    for (int q = 0; q < 4; ++q) {
      const int gq = g + q * step;
      const int neg = (gq >= P);
      const int p = neg ? gq - P : gq;
      const int* ia = neg ? en : ep;
      na[q] = ia[p]; nb[q] = ia[P + p];
    }
    uint4 ra[4], rb[4];
#pragma unroll
    for (int q = 0; q < 4; ++q) {
      ra[q] = *(const uint4*)(zp + (size_t)na[q] * 64 + sub * 16);
      rb[q] = *(const uint4*)(zp + (size_t)nb[q] * 64 + sub * 16);
    }
    float s[4] = {0.f, 0.f, 0.f, 0.f};
#pragma unroll
    for (int q = 0; q < 4; ++q) DOTV(ra[q], rb[q], s[q])
#pragma unroll
    for (int off = 2; off; off >>= 1)
#pragma unroll
      for (int q = 0; q < 4; ++q) s[q] += __shfl_down(s[q], off, 4);
    if (sub == 0)
#pragma unroll
      for (int q = 0; q < 4; ++q) sp[g + q * step] = s[q];
  }
  for (; g < 2 * P; g += step) {
    const int neg = (g >= P);
    const int p = neg ? g - P : g;
    const int* ia = neg ? en : ep;
    const int na = ia[p], nb = ia[P + p];
    const uint4 ra = *(const uint4*)(zp + (size_t)na * 64 + sub * 16);
    const uint4 rb = *(const uint4*)(zp + (size_t)nb * 64 + sub * 16);
    float s = 0.f;
    DOTV(ra, rb, s)
#pragma unroll
    for (int off = 2; off; off >>= 1) s += __shfl_down(s, off, 4);
    if (sub == 0) sp[g] = s;
  }
}

// ---------------- loss pass1: plane1 dots (masked) + sp + log-sigmoid (4-way ILP)
__global__ __launch_bounds__(256) void loss_p1(
    const u8* __restrict__ zp1, const int* __restrict__ ep,
    const int* __restrict__ en, int P, const float* __restrict__ sp,
    float* __restrict__ acc)
{
  __shared__ float red[8];
  const int tid = threadIdx.x;
  const int lane = tid & 63, wib = tid >> 6;
  const int sub = tid & 3;
  const int slot0 = blockIdx.x * 64 + (tid >> 2);
  const int step = gridDim.x * 64;
  float tp = 0.f, tn = 0.f;
  int g = slot0;
  for (; g + 3 * step < 2 * P; g += 4 * step) {
    int neg[4], na[4], nb[4];
#pragma unroll
    for (int q = 0; q < 4; ++q) {
      const int gq = g + q * step;
      neg[q] = (gq >= P);
      const int p = neg[q] ? gq - P : gq;
      const int* ia = neg[q] ? en : ep;
      na[q] = ia[p]; nb[q] = ia[P + p];
    }
    float s[4] = {0.f, 0.f, 0.f, 0.f};
    if (sub < 3) {   // bytes [0,36) valid: sub0-1 full, sub2 keeps .x only
      uint4 ra[4], rb[4];
#pragma unroll
      for (int q = 0; q < 4; ++q) {
        ra[q] = *(const uint4*)(zp1 + (size_t)na[q] * 64 + sub * 16);
        rb[q] = *(const uint4*)(zp1 + (size_t)nb[q] * 64 + sub * 16);
        if (sub == 2) {
          ra[q].y = ra[q].z = ra[q].w = 0u;
          rb[q].y = rb[q].z = rb[q].w = 0u;
        }
      }
#pragma unroll
      for (int q = 0; q < 4; ++q) DOTV(ra[q], rb[q], s[q])
    }
#pragma unroll
    for (int off = 2; off; off >>= 1)
#pragma unroll
      for (int q = 0; q < 4; ++q) s[q] += __shfl_down(s[q], off, 4);
    if (sub == 0) {
#pragma unroll
      for (int q = 0; q < 4; ++q) {
        const float st = s[q] + sp[g + q * step];
        const float sig = 1.f / (1.f + expf(-st));
        if (neg[q]) tn += logf(1.f - sig + 1e-15f); else tp += logf(sig + 1e-15f);
      }
    }
  }
  for (; g < 2 * P; g += step) {
    const int neg = (g >= P);
    const int p = neg ? g - P : g;
    const int* ia = neg ? en : ep;
    const int na = ia[p], nb = ia[P + p];
    float s = 0.f;
    if (sub < 3) {
      uint4 ra = *(const uint4*)(zp1 + (size_t)na * 64 + sub * 16);
      uint4 rb = *(const uint4*)(zp1 + (size_t)nb * 64 + sub * 16);
      if (sub == 2) { ra.y = ra.z = ra.w = 0u; rb.y = rb.z = rb.w = 0u; }
      DOTV(ra, rb, s)
    }
#pragma unroll
    for (int off = 2; off; off >>= 1) s += __shfl_down(s, off, 4);
    if (sub == 0) {
      const float st = s + sp[g];
      const float sig = 1.f / (1.f + expf(-st));
      if (neg) tn += logf(1.f - sig + 1e-15f); else tp += logf(sig + 1e-15f);
    }
  }
  tp += __shfl_down(tp, 32, 64); tn += __shfl_down(tn, 32, 64);
  tp += __shfl_down(tp, 16, 64); tn += __shfl_down(tn, 16, 64);
  tp += __shfl_down(tp, 8, 64);  tn += __shfl_down(tn, 8, 64);
  tp += __shfl_down(tp, 4, 64);  tn += __shfl_down(tn, 4, 64);
  if (lane == 0) { red[wib] = tp; red[4 + wib] = tn; }
  __syncthreads();
  if (tid == 0) {
    atomicAdd(acc + 0, red[0] + red[1] + red[2] + red[3]);
    atomicAdd(acc + 1, red[4] + red[5] + red[6] + red[7]);
  }
}
#undef DOTV

// ---------------- fused gather2 + final
__global__ void gather2_final(
    const float* __restrict__ t1, const float* __restrict__ t0,
    const int* __restrict__ ptr, const int2* __restrict__ csr,
    const float* __restrict__ accs,
    const float* __restrict__ c1, const float* __restrict__ c2,
    float* __restrict__ out, int M, float invP)
{
  const int i = blockIdx.x * blockDim.x + threadIdx.x;
  if (i < M) {
    float a0 = 0.f, a1 = 0.f;
    const int beg = ptr[i], end = ptr[i + 1];
    int p = beg;
    for (; p + 4 <= end; p += 4) {
      const int2 e0 = csr[p], e1 = csr[p + 1], e2 = csr[p + 2], e3 = csr[p + 3];
      const float w0 = __int_as_float(e0.y), w1 = __int_as_float(e1.y);
      const float w2 = __int_as_float(e2.y), w3 = __int_as_float(e3.y);
      const float2 v0 = *(const float2*)(t1 + (size_t)e0.x * 2);
      const float2 v1 = *(const float2*)(t1 + (size_t)e1.x * 2);
      const float2 v2 = *(const float2*)(t1 + (size_t)e2.x * 2);
      const float2 v3 = *(const float2*)(t1 + (size_t)e3.x * 2);
      a0 = fmaf(w0, v0.x, a0); a1 = fmaf(w0, v0.y, a1);
      a0 = fmaf(w1, v1.x, a0); a1 = fmaf(w1, v1.y, a1);
      a0 = fmaf(w2, v2.x, a0); a1 = fmaf(w2, v2.y, a1);
      a0 = fmaf(w3, v3.x, a0); a1 = fmaf(w3, v3.y, a1);
    }
    for (; p < end; ++p) {
      const int2 eq = csr[p]; const float wq = __int_as_float(eq.y);
      const float2 v = *(const float2*)(t1 + (size_t)eq.x * 2);
      a0 = fmaf(wq, v.x, a0); a1 = fmaf(wq, v.y, a1);
    }
    const float2 base = *(const float2*)(t0 + (size_t)i * 2);
    *(float2*)(out + (size_t)i * 2) = make_float2(base.x + a0, base.y + a1);
  }
  if (i == 0) {
    out[2 * M + 0] = -(accs[0] + accs[1]) * invP;
    out[2 * M + 1] = c1[0];
    out[2 * M + 2] = c2[0];
  }
}

extern "C" void kernel_launch(void* const* d_in, const int* in_sizes, int n_in,
                              void* d_out, int out_size, void* d_ws, size_t ws_size,
                              hipStream_t stream)
{
  const float* x   = (const float*)d_in[0];
  const int*   ei  = (const int*)d_in[1];
  const int*   ep  = (const int*)d_in[2];
  const int*   en  = (const int*)d_in[3];
  const float* W1  = (const float*)d_in[4];
  const float* b1  = (const float*)d_in[5];
  const float* W2  = (const float*)d_in[6];
  const float* b2  = (const float*)d_in[7];
  const float* W3  = (const float*)d_in[8];
  const float* b3  = (const float*)d_in[9];
  const float* l1W = (const float*)d_in[10];
  const float* l1b = (const float*)d_in[11];
  const float* l2W = (const float*)d_in[12];
  const float* l2b = (const float*)d_in[13];
  const float* c1  = (const float*)d_in[14];
  const float* c2  = (const float*)d_in[15];
  float* out = (float*)d_out;

  const int M = in_sizes[0] / 128;  // 50000
  const int E = in_sizes[1] / 2;    // 800000
  const int P = in_sizes[2] / 2;    // 400000
  const int* src = ei;
  const int* dst = ei + E;
  const int nb_scan = (M + 255) / 256;

  float* ws = (float*)d_ws;
  size_t o = 0;
  float*    dinv = ws + o;            o += 50176;
  int*      cnt  = (int*)(ws + o);    o += (size_t)M;
  int*      ptr  = (int*)(ws + o);    o += (size_t)M + 8;
  int*      bsum = (int*)(ws + o);    o += 256;
  int2*     csr  = (int2*)(ws + o);   o += (size_t)E * 2;
  ushort_t* rank = (ushort_t*)(ws + o); o += (size_t)E / 2;
  ushort_t* xb   = (ushort_t*)(ws + o); o += (size_t)M * 64;   // bf16 [M][128]
  u8*       xf8  = (u8*)(ws + o);     o += (size_t)M * 32;     // fp8 2 planes [M][64]
  ushort_t* tx0b = (ushort_t*)(ws + o); o += (size_t)M * 64;   // bf16 [M][128]
  ushort_t* W1t  = (ushort_t*)(ws + o); o += 40960;
  ushort_t* W2t  = (ushort_t*)(ws + o); o += 35840;
  ushort_t* Wlt  = (ushort_t*)(ws + o); o += 14336;
  u8*       h8   = (u8*)(ws + o);     o += (size_t)M * 160;    // region 32MB: h fp8 [M][320] uses 16MB
  float*    Ar   = ws + o;            o += (size_t)M * 128;    // f32 stride128, 25.6MB
  u8*       Brh  = (u8*)(ws + o);     o += (size_t)M * 32;     // fp8 2 planes
  u8*       zf8  = (u8*)(ws + o);     o += (size_t)M * 32;     // fp8 2 planes
  float*    sp   = ws + o;            o += (size_t)2 * P;
  float*    t0   = ws + o;            o += (size_t)M * 2;
  float*    t1   = ws + o;            o += (size_t)M * 2;
  float*    accs = ws + o;            o += 8;
  unsigned* partS = (unsigned*)h8;   // aliases (32MB region), dead during CSR build
  unsigned* partD = (unsigned*)Ar;
  const size_t pstride = (size_t)M * 64;

  // packing + conversion
  const int n4 = M * 32;
  pack_cvt<<<(n4 + 182272 + 255) / 256, 256, 0, stream>>>(
      x, xb, xf8, n4, M, W1, W2, l1W, l2W, W1t, W2t, Wlt);

  // CSR build (no global atomics)
  hist2<<<NB_H, 256, 0, stream>>>(src, dst, E, M, partS, partD, rank);
  reduce_base2<<<(2 * PW + 255) / 256, 256, 0, stream>>>(partS, partD, dinv, cnt, M);
  scan_local<<<nb_scan, 256, 0, stream>>>(cnt, ptr, bsum, M);
  scan_bsum<<<1, 256, 0, stream>>>(bsum, nb_scan, accs);
  scan_add<<<nb_scan, 256, 0, stream>>>(ptr, bsum, M, E);
  fill_csr2<<<(E + 255) / 256, 256, 0, stream>>>(src, dst, dinv, ptr, partD, rank, csr, E);

  const int gB = (M + 63) / 64;
  const int gP4 = (M * 4 + 255) / 256;

  // conv1: two plane passes, then GEMM (h out as fp8)
  gather128p<0><<<gP4, 256, 0, stream>>>(xf8, tx0b, ptr, csr, M);
  gather128p<1><<<gP4, 256, 0, stream>>>(xf8 + pstride, tx0b, ptr, csr, M);
  gemm_mfma<0, 320, 256><<<gB, 256, 0, stream>>>(
      xb, tx0b, W1t, b1, nullptr, nullptr, nullptr, nullptr, h8, nullptr, nullptr, nullptr, M);

  // conv2 (A = h fp8)
  gemm_mfma<1, 224, 320><<<gB, 256, 0, stream>>>(
      (const ushort_t*)h8, nullptr, W2t, b2, nullptr, nullptr, nullptr, nullptr,
      Ar, Brh, nullptr, nullptr, M);
  gather100p_x1<0><<<gP4, 256, 0, stream>>>(Brh, Ar, ptr, csr, M);
  gather100p_x1<1><<<gP4, 256, 0, stream>>>(Brh + pstride, Ar, ptr, csr, M);

  // lins + fused w3
  gemm_mfma<2, 224, 128><<<gB, 256, 0, stream>>>(
      xb, nullptr, Wlt, l1b, l2b, Ar /*x1*/, W3, b3, nullptr, zf8, t0, t1, M);

  // loss: two plane passes (both ILP-4)
  loss_p0<<<2048, 256, 0, stream>>>(zf8, ep, en, P, sp);
  loss_p1<<<2048, 256, 0, stream>>>(zf8 + pstride, ep, en, P, sp, accs);

  // conv3 propagation + final
  gather2_final<<<(M + 255) / 256, 256, 0, stream>>>(t1, t0, ptr, csr,
                                                     accs, c1, c2, out, M, 1.0f / (float)P);
}

// Round 14
// 471.398 us; speedup vs baseline: 1.0656x; 1.0524x over previous
//
#include <hip/hip_runtime.h>
#include <math.h>

// MTGCN R12 = R9 structure (best: single-pass eighth-wave gathers/loss, full 128B
// fp8 rows) + h stored fp8 [M][320] (VAR0 writes fp8, VAR1 converts fp8->bf16 in
// A-staging). Plane-split reverted: R10/R11 proved random-access cost is per-row,
// not per-byte — splitting doubled the latency-capped pass count.
// Atomic-free CSR (hist2 + rank + reduce_base2), bf16 MFMA GEMMs, no memsets.

typedef unsigned short ushort_t;
typedef unsigned char u8;
typedef __attribute__((ext_vector_type(8))) __bf16 bf16x8;
typedef __attribute__((ext_vector_type(8))) short s16x8;
typedef __attribute__((ext_vector_type(4))) float f32x4;
typedef __attribute__((ext_vector_type(2))) float f32x2;

#define NB_H 256
#define HW 12500
#define PW 25000

__device__ __forceinline__ f32x4 mfma16x16x32(s16x8 a, s16x8 b, f32x4 c) {
  return __builtin_amdgcn_mfma_f32_16x16x32_bf16(
      __builtin_bit_cast(bf16x8, a), __builtin_bit_cast(bf16x8, b), c, 0, 0, 0);
}
__device__ __forceinline__ ushort_t f2bf(float f) {
  union { float f; unsigned u; } c; c.f = f;
  unsigned r = (c.u + 0x7FFFu + ((c.u >> 16) & 1u)) >> 16;
  return (ushort_t)r;
}
__device__ __forceinline__ f32x2 cvt2lo(unsigned u) {
  return __builtin_amdgcn_cvt_pk_f32_fp8((int)u, false);
}
__device__ __forceinline__ f32x2 cvt2hi(unsigned u) {
  return __builtin_amdgcn_cvt_pk_f32_fp8((int)u, true);
}
__device__ __forceinline__ u8 f2fp8(float f) {
  return (u8)(__builtin_amdgcn_cvt_pk_fp8_f32(f, 0.f, 0, false) & 0xff);
}

// =======================================================================
// MFMA GEMM. VAR0: A=[xb|tx0b] bf16 -> h fp8 [M][320] relu+b1.
// VAR1: A=h fp8 (convert->bf16 in staging) -> Ar f32 s128 / Brh fp8 s128.
// VAR2: A=xb bf16 -> zf8 fp8 s128 + t0/t1 via w3 shuffle reduce.
// =======================================================================
template<int VAR, int NT, int KTOT>
__global__ __launch_bounds__(256) void gemm_mfma(
    const ushort_t* __restrict__ A0, const ushort_t* __restrict__ A1,
    const ushort_t* __restrict__ Wt,
    const float* __restrict__ bias0, const float* __restrict__ bias1,
    const float* __restrict__ x1,
    const float* __restrict__ W3c, const float* __restrict__ b3c,
    void* __restrict__ out0, void* __restrict__ out1,
    float* __restrict__ t0g, float* __restrict__ t1g, int M)
{
  constexpr int NF = NT / 32;
  __shared__ __align__(16) ushort_t As[64 * 40];
  __shared__ __align__(16) ushort_t Bs[NT * 40];
  __shared__ float w3s[400];
  const int tid  = threadIdx.x;
  const int lane = tid & 63, w = tid >> 6;
  const int m0 = blockIdx.x * 64;
  const int wm = (w & 1) * 32, wn = (w >> 1) * (NT / 2);
  if (VAR == 2) { for (int i = tid; i < 400; i += 256) w3s[i] = W3c[i]; }
  f32x4 acc[2][NF];
#pragma unroll
  for (int i = 0; i < 2; ++i)
#pragma unroll
    for (int j = 0; j < NF; ++j) acc[i][j] = (f32x4){0.f, 0.f, 0.f, 0.f};

  for (int k0 = 0; k0 < KTOT; k0 += 32) {
    { // A stage
      const int r = tid >> 2, c8 = (tid & 3) * 8;
      const int gm = m0 + r;
      uint4 v = {0u, 0u, 0u, 0u};
      if (gm < M) {
        if (VAR == 1) {  // fp8 h: load 8 bytes, convert to 8 bf16
          const u8* s8 = (const u8*)A0 + (size_t)gm * 320 + k0 + c8;
          const uint2 r8 = *(const uint2*)s8;
          const f32x2 f0 = cvt2lo(r8.x), f1 = cvt2hi(r8.x);
          const f32x2 f2 = cvt2lo(r8.y), f3 = cvt2hi(r8.y);
          v.x = (unsigned)f2bf(f0.x) | ((unsigned)f2bf(f0.y) << 16);
          v.y = (unsigned)f2bf(f1.x) | ((unsigned)f2bf(f1.y) << 16);
          v.z = (unsigned)f2bf(f2.x) | ((unsigned)f2bf(f2.y) << 16);
          v.w = (unsigned)f2bf(f3.x) | ((unsigned)f2bf(f3.y) << 16);
        } else {
          const ushort_t* srcp;
          if (VAR == 0) srcp = (k0 < 128) ? A0 + (size_t)gm * 128 + k0 + c8
                                          : A1 + (size_t)gm * 128 + (k0 - 128) + c8;
          else srcp = A0 + (size_t)gm * 128 + k0 + c8;
          v = *(const uint4*)srcp;
        }
      }
      *(uint4*)&As[r * 40 + c8] = v;
    }
    { // B stage
      const int c8 = (tid & 3) * 8;
#pragma unroll
      for (int i = 0; i < (NT * 4 + 255) / 256; ++i) {
        const int r = (tid >> 2) + i * 64;
        if (r < NT)
          *(uint4*)&Bs[r * 40 + c8] = *(const uint4*)(Wt + (size_t)r * KTOT + k0 + c8);
      }
    }
    __syncthreads();
    s16x8 af[2], bfr[NF];
#pragma unroll
    for (int mi = 0; mi < 2; ++mi)
      af[mi] = *(const s16x8*)&As[(wm + mi * 16 + (lane & 15)) * 40 + (lane >> 4) * 8];
#pragma unroll
    for (int ni = 0; ni < NF; ++ni)
      bfr[ni] = *(const s16x8*)&Bs[(wn + ni * 16 + (lane & 15)) * 40 + (lane >> 4) * 8];
#pragma unroll
    for (int mi = 0; mi < 2; ++mi)
#pragma unroll
      for (int ni = 0; ni < NF; ++ni)
        acc[mi][ni] = mfma16x16x32(af[mi], bfr[ni], acc[mi][ni]);
    __syncthreads();
  }

  if (VAR == 2) {
#pragma unroll
    for (int mi = 0; mi < 2; ++mi)
#pragma unroll
      for (int r = 0; r < 4; ++r) {
        const int gRow = m0 + wm + mi * 16 + ((lane >> 4) << 2) + r;
        float p0 = 0.f, p1 = 0.f, p2 = 0.f, p3 = 0.f;
#pragma unroll
        for (int ni = 0; ni < NF; ++ni) {
          const int col = wn + ni * 16 + (lane & 15);
          const float v = acc[mi][ni][r];
          if (gRow < M) {
            if (col < 100) {
              const float x2v = x1[(size_t)gRow * 128 + col] + fmaxf(v + bias0[col], 0.f);
              p0 = fmaf(x2v, w3s[col * 2 + 0], p0);
              p1 = fmaf(x2v, w3s[col * 2 + 1], p1);
              p2 = fmaf(x2v, w3s[200 + col * 2 + 0], p2);
              p3 = fmaf(x2v, w3s[200 + col * 2 + 1], p3);
            } else if (col < 200) {
              const int c = col - 100;
              ((u8*)out1)[(size_t)gRow * 128 + c] =
                  f2fp8(x1[(size_t)gRow * 128 + c] + fmaxf(v + bias1[c], 0.f));
            }
          }
        }
        if (wn == 0) {
#pragma unroll
          for (int off = 8; off; off >>= 1) {
            p0 += __shfl_down(p0, off, 16);
            p1 += __shfl_down(p1, off, 16);
            p2 += __shfl_down(p2, off, 16);
            p3 += __shfl_down(p3, off, 16);
          }
          if ((lane & 15) == 0 && gRow < M) {
            t0g[(size_t)gRow * 2 + 0] = p0 + b3c[0];
            t0g[(size_t)gRow * 2 + 1] = p1 + b3c[1];
            t1g[(size_t)gRow * 2 + 0] = p2;
            t1g[(size_t)gRow * 2 + 1] = p3;
          }
        }
      }
  } else {
#pragma unroll
    for (int mi = 0; mi < 2; ++mi)
#pragma unroll
      for (int ni = 0; ni < NF; ++ni)
#pragma unroll
        for (int r = 0; r < 4; ++r) {
          const int gRow = m0 + wm + mi * 16 + ((lane >> 4) << 2) + r;
          const int col  = wn + ni * 16 + (lane & 15);
          if (gRow >= M) continue;
          const float v = acc[mi][ni][r];
          if (VAR == 0) {
            ((u8*)out0)[(size_t)gRow * 320 + col] =
                (col < 300) ? f2fp8(fmaxf(v + bias0[col], 0.f)) : (u8)0;
          } else {
            if (col < 100) ((float*)out0)[(size_t)gRow * 128 + col] = v + bias0[col];
            else if (col < 200) ((u8*)out1)[(size_t)gRow * 128 + (col - 100)] = f2fp8(v);
          }
        }
  }
}

// ---------------- fused conversion + weight packing ----------------
__global__ void pack_cvt(const float* __restrict__ x, ushort_t* __restrict__ xb,
                         u8* __restrict__ xf8, int n4,
                         const float* __restrict__ W1, const float* __restrict__ W2,
                         const float* __restrict__ l1W, const float* __restrict__ l2W,
                         ushort_t* __restrict__ W1t, ushort_t* __restrict__ W2t,
                         ushort_t* __restrict__ Wlt) {
  const int i = blockIdx.x * 256 + threadIdx.x;
  if (i < n4) {
    const float4 v = ((const float4*)x)[i];
    ushort4 o; o.x = f2bf(v.x); o.y = f2bf(v.y); o.z = f2bf(v.z); o.w = f2bf(v.w);
    ((ushort4*)xb)[i] = o;
    int p = 0;
    p = __builtin_amdgcn_cvt_pk_fp8_f32(v.x, v.y, p, false);
    p = __builtin_amdgcn_cvt_pk_fp8_f32(v.z, v.w, p, true);
    ((unsigned*)xf8)[i] = (unsigned)p;
    return;
  }
  const int j = i - n4;
  if (j < 81920) {                       // W1t [320][256]
    const int n = j >> 8, k = j & 255;
    float v = 0.f;
    if (n < 300) v = (k < 128) ? W1[k * 300 + n] : W1[38400 + (k - 128) * 300 + n];
    W1t[j] = f2bf(v);
  } else if (j < 153600) {               // W2t [224][320]
    const int jj = j - 81920;
    const int n = jj / 320, k = jj - n * 320;
    float v = 0.f;
    if (n < 200 && k < 300) v = W2[(n < 100 ? 0 : 30000) + k * 100 + (n % 100)];
    W2t[jj] = f2bf(v);
  } else if (j < 182272) {               // Wlt [224][128]
    const int jj = j - 153600;
    const int n = jj >> 7, k = jj & 127;
    float v = 0.f;
    if (n < 100) v = l1W[n * 128 + k];
    else if (n < 200) v = l2W[(n - 100) * 128 + k];
    Wlt[jj] = f2bf(v);
  }
}

// ---------------- histogram + rank ----------------
__global__ __launch_bounds__(256) void hist2(
    const int* __restrict__ src, const int* __restrict__ dst, int E, int M,
    unsigned* __restrict__ partS, unsigned* __restrict__ partD,
    ushort_t* __restrict__ rank)
{
  __shared__ unsigned hist[HW];
  const int b = blockIdx.x;
  const int cs = (E + NB_H - 1) / NB_H;
  const int e0 = b * cs;
  const int e1 = (e0 + cs < E) ? e0 + cs : E;
  for (int isD = 0; isD < 2; ++isD) {
    const int* keys = isD ? dst : src;
    unsigned* part = isD ? partD : partS;
    for (int r = 0; r < 2; ++r) {
      const int klo = r * 2 * HW;
      for (int i = threadIdx.x; i < HW; i += 256) hist[i] = 0;
      __syncthreads();
      for (int e = e0 + threadIdx.x; e < e1; e += 256) {
        const int k = keys[e] - klo;
        if ((unsigned)k < (unsigned)(2 * HW)) {
          const unsigned old = atomicAdd(&hist[k >> 1], (k & 1) ? 0x10000u : 1u);
          if (isD) rank[e] = (ushort_t)((old >> ((k & 1) * 16)) & 0xffffu);
        }
      }
      __syncthreads();
      for (int i = threadIdx.x; i < HW; i += 256)
        part[(size_t)b * PW + r * HW + i] = hist[i];
      __syncthreads();
    }
  }
}

// ---------------- reduce_base2
__global__ __launch_bounds__(256) void reduce_base2(
    const unsigned* __restrict__ partS, unsigned* __restrict__ partD,
    float* __restrict__ dinv, int* __restrict__ cnt, int M)
{
  const int t = blockIdx.x * 256 + threadIdx.x;
  if (t < PW) {
    const int i = t;
    unsigned ssum = 0;
    for (int b = 0; b < NB_H; b += 8) {
      unsigned v[8];
#pragma unroll
      for (int q = 0; q < 8; ++q) v[q] = partS[(size_t)(b + q) * PW + i];
#pragma unroll
      for (int q = 0; q < 8; ++q) ssum += v[q];
    }
    const int k = 2 * i;
    const unsigned s0 = ssum & 0xffffu, s1 = ssum >> 16;
    if (k < M) dinv[k] = s0 ? 1.f / sqrtf((float)s0) : 0.f;
    if (k + 1 < M) dinv[k + 1] = s1 ? 1.f / sqrtf((float)s1) : 0.f;
  } else if (t < 2 * PW) {
    const int i = t - PW;
    unsigned run = 0;
    for (int b = 0; b < NB_H; b += 8) {
      unsigned v[8], pre[8];
#pragma unroll
      for (int q = 0; q < 8; ++q) v[q] = partD[(size_t)(b + q) * PW + i];
#pragma unroll
      for (int q = 0; q < 8; ++q) { pre[q] = run; run += v[q]; }
#pragma unroll
      for (int q = 0; q < 8; ++q) partD[(size_t)(b + q) * PW + i] = pre[q];
    }
    const int k = 2 * i;
    if (k < M) cnt[k] = (int)(run & 0xffffu);
    if (k + 1 < M) cnt[k + 1] = (int)(run >> 16);
  }
}

// ---------------- scan
__global__ void scan_local(const int* __restrict__ cnt, int* __restrict__ ptr,
                           int* __restrict__ bsum, int n)
{
  __shared__ int tmp[256];
  const int i = blockIdx.x * 256 + threadIdx.x;
  const int v = (i < n) ? cnt[i] : 0;
  tmp[threadIdx.x] = v;
  __syncthreads();
  for (int off = 1; off < 256; off <<= 1) {
    const int t = (threadIdx.x >= off) ? tmp[threadIdx.x - off] : 0;
    __syncthreads();
    tmp[threadIdx.x] += t;
    __syncthreads();
  }
  if (i < n) ptr[i] = tmp[threadIdx.x] - v;
  if (threadIdx.x == 255) bsum[blockIdx.x] = tmp[255];
}
__global__ void scan_bsum(int* __restrict__ bsum, int nb, float* __restrict__ accs) {
  __shared__ int tmp[256];
  if (threadIdx.x < 2) accs[threadIdx.x] = 0.f;
  const int v = (threadIdx.x < nb) ? bsum[threadIdx.x] : 0;
  tmp[threadIdx.x] = v;
  __syncthreads();
  for (int off = 1; off < 256; off <<= 1) {
    const int t = (threadIdx.x >= off) ? tmp[threadIdx.x - off] : 0;
    __syncthreads();
    tmp[threadIdx.x] += t;
    __syncthreads();
  }
  if (threadIdx.x < nb) bsum[threadIdx.x] = tmp[threadIdx.x] - v;
}
__global__ void scan_add(int* __restrict__ ptr, const int* __restrict__ bsum, int n, int E) {
  const int i = blockIdx.x * 256 + threadIdx.x;
  if (i < n) ptr[i] += bsum[blockIdx.x];
  if (i == 0) ptr[n] = E;
}

// ---------------- atomic-free fill
__global__ void fill_csr2(const int* __restrict__ src, const int* __restrict__ dst,
                          const float* __restrict__ dinv, const int* __restrict__ ptr,
                          const unsigned* __restrict__ base32,
                          const ushort_t* __restrict__ rank,
                          int2* __restrict__ csr, int E)
{
  const int e = blockIdx.x * 256 + threadIdx.x;
  if (e >= E) return;
  const int cs = (E + NB_H - 1) / NB_H;
  const int b = e / cs;
  const int s = src[e], d = dst[e];
  const unsigned bv = base32[(size_t)b * PW + (d >> 1)];
  const int base = (int)((bv >> ((d & 1) * 16)) & 0xffffu);
  const int pos = ptr[d] + base + (int)rank[e];
  const float w = -dinv[s] * dinv[d];
  csr[pos] = make_int2(s, __float_as_int(w));
}

#define ACCV(u, ww) { f32x2 t; \
  t = cvt2lo(u.x); a[0]  = fmaf(ww, t.x, a[0]);  a[1]  = fmaf(ww, t.y, a[1]);  \
  t = cvt2hi(u.x); a[2]  = fmaf(ww, t.x, a[2]);  a[3]  = fmaf(ww, t.y, a[3]);  \
  t = cvt2lo(u.y); a[4]  = fmaf(ww, t.x, a[4]);  a[5]  = fmaf(ww, t.y, a[5]);  \
  t = cvt2hi(u.y); a[6]  = fmaf(ww, t.x, a[6]);  a[7]  = fmaf(ww, t.y, a[7]);  \
  t = cvt2lo(u.z); a[8]  = fmaf(ww, t.x, a[8]);  a[9]  = fmaf(ww, t.y, a[9]);  \
  t = cvt2hi(u.z); a[10] = fmaf(ww, t.x, a[10]); a[11] = fmaf(ww, t.y, a[11]); \
  t = cvt2lo(u.w); a[12] = fmaf(ww, t.x, a[12]); a[13] = fmaf(ww, t.y, a[13]); \
  t = cvt2hi(u.w); a[14] = fmaf(ww, t.x, a[14]); a[15] = fmaf(ww, t.y, a[15]); }

// ---------------- gather128: eighth-wave, 8-edge unroll
__global__ __launch_bounds__(256) void gather128e(
    const u8* __restrict__ xf8, ushort_t* __restrict__ txb,
    const int* __restrict__ ptr, const int2* __restrict__ csr, int M)
{
  const int node = (blockIdx.x * 256 + threadIdx.x) >> 3;
  const int sub  = threadIdx.x & 7;
  if (node >= M) return;
  const int beg = ptr[node], end = ptr[node + 1];
  float a[16] = {};
  int p = beg;
  for (; p + 8 <= end; p += 8) {
    int2 e[8];
#pragma unroll
    for (int q = 0; q < 8; ++q) e[q] = csr[p + q];
    uint4 v[8];
#pragma unroll
    for (int q = 0; q < 8; ++q)
      v[q] = *(const uint4*)(xf8 + (size_t)e[q].x * 128 + sub * 16);
#pragma unroll
    for (int q = 0; q < 8; ++q) { const float wq = __int_as_float(e[q].y); ACCV(v[q], wq) }
  }
  for (; p < end; ++p) {
    const int2 eq = csr[p]; const float wq = __int_as_float(eq.y);
    const uint4 v = *(const uint4*)(xf8 + (size_t)eq.x * 128 + sub * 16);
    ACCV(v, wq)
  }
  uint4 o1, o2;
  o1.x = (unsigned)f2bf(a[0])  | ((unsigned)f2bf(a[1])  << 16);
  o1.y = (unsigned)f2bf(a[2])  | ((unsigned)f2bf(a[3])  << 16);
  o1.z = (unsigned)f2bf(a[4])  | ((unsigned)f2bf(a[5])  << 16);
  o1.w = (unsigned)f2bf(a[6])  | ((unsigned)f2bf(a[7])  << 16);
  o2.x = (unsigned)f2bf(a[8])  | ((unsigned)f2bf(a[9])  << 16);
  o2.y = (unsigned)f2bf(a[10]) | ((unsigned)f2bf(a[11]) << 16);
  o2.z = (unsigned)f2bf(a[12]) | ((unsigned)f2bf(a[13]) << 16);
  o2.w = (unsigned)f2bf(a[14]) | ((unsigned)f2bf(a[15]) << 16);
  ushort_t* dstp = txb + (size_t)node * 128 + sub * 16;
  *(uint4*)dstp = o1;
  *(uint4*)(dstp + 8) = o2;
}

// ---------------- fused gather100 + x1 (eighth-wave, 8-edge unroll)
// Brh cols 100-127 garbage -> accumulates into dead Ar cols (never read).
__global__ __launch_bounds__(256) void gather100e_x1(
    const u8* __restrict__ Brh, float* __restrict__ Ar,
    const int* __restrict__ ptr, const int2* __restrict__ csr, int M)
{
  const int node = (blockIdx.x * 256 + threadIdx.x) >> 3;
  const int sub  = threadIdx.x & 7;
  if (node >= M) return;
  const int beg = ptr[node], end = ptr[node + 1];
  float a[16] = {};
  int p = beg;
  for (; p + 8 <= end; p += 8) {
    int2 e[8];
#pragma unroll
    for (int q = 0; q < 8; ++q) e[q] = csr[p + q];
    uint4 v[8];
#pragma unroll
    for (int q = 0; q < 8; ++q)
      v[q] = *(const uint4*)(Brh + (size_t)e[q].x * 128 + sub * 16);
#pragma unroll
    for (int q = 0; q < 8; ++q) { const float wq = __int_as_float(e[q].y); ACCV(v[q], wq) }
  }
  for (; p < end; ++p) {
    const int2 eq = csr[p]; const float wq = __int_as_float(eq.y);
    const uint4 v = *(const uint4*)(Brh + (size_t)eq.x * 128 + sub * 16);
    ACCV(v, wq)
  }
  float* dstp = Ar + (size_t)node * 128 + sub * 16;
#pragma unroll
  for (int q = 0; q < 4; ++q) {
    float4 b = *(const float4*)(dstp + q * 4);
    b.x = fmaxf(b.x + a[q * 4 + 0], 0.f);
    b.y = fmaxf(b.y + a[q * 4 + 1], 0.f);
    b.z = fmaxf(b.z + a[q * 4 + 2], 0.f);
    b.w = fmaxf(b.w + a[q * 4 + 3], 0.f);
    *(float4*)(dstp + q * 4) = b;
  }
}
#undef ACCV

// ---------------- loss: eighth-wave per pair, 4-way pair ILP.
// zf8 cols 100-127 garbage: mask bytes >=100 on BOTH operands.
__device__ __forceinline__ void maskrow(uint4& r, int sub) {
  if (sub >= 6) { r.y = 0u; r.z = 0u; r.w = 0u; if (sub == 7) r.x = 0u; }
}
#define DOTV(uu, vv, s) { f32x2 p_, q_; \
  p_ = cvt2lo(uu.x); q_ = cvt2lo(vv.x); s = fmaf(p_.x, q_.x, s); s = fmaf(p_.y, q_.y, s); \
  p_ = cvt2hi(uu.x); q_ = cvt2hi(vv.x); s = fmaf(p_.x, q_.x, s); s = fmaf(p_.y, q_.y, s); \
  p_ = cvt2lo(uu.y); q_ = cvt2lo(vv.y); s = fmaf(p_.x, q_.x, s); s = fmaf(p_.y, q_.y, s); \
  p_ = cvt2hi(uu.y); q_ = cvt2hi(vv.y); s = fmaf(p_.x, q_.x, s); s = fmaf(p_.y, q_.y, s); \
  p_ = cvt2lo(uu.z); q_ = cvt2lo(vv.z); s = fmaf(p_.x, q_.x, s); s = fmaf(p_.y, q_.y, s); \
  p_ = cvt2hi(uu.z); q_ = cvt2hi(vv.z); s = fmaf(p_.x, q_.x, s); s = fmaf(p_.y, q_.y, s); \
  p_ = cvt2lo(uu.w); q_ = cvt2lo(vv.w); s = fmaf(p_.x, q_.x, s); s = fmaf(p_.y, q_.y, s); \
  p_ = cvt2hi(uu.w); q_ = cvt2hi(vv.w); s = fmaf(p_.x, q_.x, s); s = fmaf(p_.y, q_.y, s); }

__global__ __launch_bounds__(256) void loss_fp8(
    const u8* __restrict__ zf8, const int* __restrict__ ep,
    const int* __restrict__ en, int P, float* __restrict__ acc)
{
  __shared__ float red[8];
  const int tid = threadIdx.x;
  const int lane = tid & 63, wib = tid >> 6;
  const int sub = tid & 7;
  const int slot0 = blockIdx.x * 32 + (tid >> 3);
  const int step = gridDim.x * 32;
  float tp = 0.f, tn = 0.f;
  int g = slot0;
  for (; g + 3 * step < 2 * P; g += 4 * step) {
    int neg[4], na[4], nb[4];
#pragma unroll
    for (int q = 0; q < 4; ++q) {
      const int gq = g + q * step;
      neg[q] = (gq >= P);
      const int p = neg[q] ? gq - P : gq;
      const int* ia = neg[q] ? en : ep;
      na[q] = ia[p]; nb[q] = ia[P + p];
    }
    uint4 ra[4], rb[4];
#pragma unroll
    for (int q = 0; q < 4; ++q) {
      ra[q] = *(const uint4*)(zf8 + (size_t)na[q] * 128 + sub * 16);
      rb[q] = *(const uint4*)(zf8 + (size_t)nb[q] * 128 + sub * 16);
      maskrow(ra[q], sub); maskrow(rb[q], sub);
    }
    float s[4] = {0.f, 0.f, 0.f, 0.f};
#pragma unroll
    for (int q = 0; q < 4; ++q) DOTV(ra[q], rb[q], s[q])
#pragma unroll
    for (int off = 4; off; off >>= 1) {
#pragma unroll
      for (int q = 0; q < 4; ++q) s[q] += __shfl_down(s[q], off, 8);
    }
    if (sub == 0) {
#pragma unroll
      for (int q = 0; q < 4; ++q) {
        const float sig = 1.f / (1.f + expf(-s[q]));
        if (neg[q]) tn += logf(1.f - sig + 1e-15f); else tp += logf(sig + 1e-15f);
      }
    }
  }
  for (; g < 2 * P; g += step) {
    const int neg = (g >= P);
    const int p = neg ? g - P : g;
    const int* ia = neg ? en : ep;
    const int na = ia[p], nb = ia[P + p];
    uint4 ra = *(const uint4*)(zf8 + (size_t)na * 128 + sub * 16);
    uint4 rb = *(const uint4*)(zf8 + (size_t)nb * 128 + sub * 16);
    maskrow(ra, sub); maskrow(rb, sub);
    float s = 0.f;
    DOTV(ra, rb, s)
#pragma unroll
    for (int off = 4; off; off >>= 1) s += __shfl_down(s, off, 8);
    if (sub == 0) {
      const float sig = 1.f / (1.f + expf(-s));
      if (neg) tn += logf(1.f - sig + 1e-15f); else tp += logf(sig + 1e-15f);
    }
  }
  tp += __shfl_down(tp, 32, 64); tn += __shfl_down(tn, 32, 64);
  tp += __shfl_down(tp, 16, 64); tn += __shfl_down(tn, 16, 64);
  tp += __shfl_down(tp, 8, 64);  tn += __shfl_down(tn, 8, 64);
  if (lane == 0) { red[wib] = tp; red[4 + wib] = tn; }
  __syncthreads();
  if (tid == 0) {
    atomicAdd(acc + 0, red[0] + red[1] + red[2] + red[3]);
    atomicAdd(acc + 1, red[4] + red[5] + red[6] + red[7]);
  }
}
#undef DOTV

// ---------------- fused gather2 + final
__global__ void gather2_final(
    const float* __restrict__ t1, const float* __restrict__ t0,
    const int* __restrict__ ptr, const int2* __restrict__ csr,
    const float* __restrict__ accs,
    const float* __restrict__ c1, const float* __restrict__ c2,
    float* __restrict__ out, int M, float invP)
{
  const int i = blockIdx.x * blockDim.x + threadIdx.x;
  if (i < M) {
    float a0 = 0.f, a1 = 0.f;
    const int beg = ptr[i], end = ptr[i + 1];
    int p = beg;
    for (; p + 4 <= end; p += 4) {
      const int2 e0 = csr[p], e1 = csr[p + 1], e2 = csr[p + 2], e3 = csr[p + 3];
      const float w0 = __int_as_float(e0.y), w1 = __int_as_float(e1.y);
      const float w2 = __int_as_float(e2.y), w3 = __int_as_float(e3.y);
      const float2 v0 = *(const float2*)(t1 + (size_t)e0.x * 2);
      const float2 v1 = *(const float2*)(t1 + (size_t)e1.x * 2);
      const float2 v2 = *(const float2*)(t1 + (size_t)e2.x * 2);
      const float2 v3 = *(const float2*)(t1 + (size_t)e3.x * 2);
      a0 = fmaf(w0, v0.x, a0); a1 = fmaf(w0, v0.y, a1);
      a0 = fmaf(w1, v1.x, a0); a1 = fmaf(w1, v1.y, a1);
      a0 = fmaf(w2, v2.x, a0); a1 = fmaf(w2, v2.y, a1);
      a0 = fmaf(w3, v3.x, a0); a1 = fmaf(w3, v3.y, a1);
    }
    for (; p < end; ++p) {
      const int2 eq = csr[p]; const float wq = __int_as_float(eq.y);
      const float2 v = *(const float2*)(t1 + (size_t)eq.x * 2);
      a0 = fmaf(wq, v.x, a0); a1 = fmaf(wq, v.y, a1);
    }
    const float2 base = *(const float2*)(t0 + (size_t)i * 2);
    *(float2*)(out + (size_t)i * 2) = make_float2(base.x + a0, base.y + a1);
  }
  if (i == 0) {
    out[2 * M + 0] = -(accs[0] + accs[1]) * invP;
    out[2 * M + 1] = c1[0];
    out[2 * M + 2] = c2[0];
  }
}

extern "C" void kernel_launch(void* const* d_in, const int* in_sizes, int n_in,
                              void* d_out, int out_size, void* d_ws, size_t ws_size,
                              hipStream_t stream)
{
  const float* x   = (const float*)d_in[0];
  const int*   ei  = (const int*)d_in[1];
  const int*   ep  = (const int*)d_in[2];
  const int*   en  = (const int*)d_in[3];
  const float* W1  = (const float*)d_in[4];
  const float* b1  = (const float*)d_in[5];
  const float* W2  = (const float*)d_in[6];
  const float* b2  = (const float*)d_in[7];
  const float* W3  = (const float*)d_in[8];
  const float* b3  = (const float*)d_in[9];
  const float* l1W = (const float*)d_in[10];
  const float* l1b = (const float*)d_in[11];
  const float* l2W = (const float*)d_in[12];
  const float* l2b = (const float*)d_in[13];
  const float* c1  = (const float*)d_in[14];
  const float* c2  = (const float*)d_in[15];
  float* out = (float*)d_out;

  const int M = in_sizes[0] / 128;  // 50000
  const int E = in_sizes[1] / 2;    // 800000
  const int P = in_sizes[2] / 2;    // 400000
  const int* src = ei;
  const int* dst = ei + E;
  const int nb_scan = (M + 255) / 256;

  float* ws = (float*)d_ws;
  size_t o = 0;
  float*    dinv = ws + o;            o += 50176;
  int*      cnt  = (int*)(ws + o);    o += (size_t)M;
  int*      ptr  = (int*)(ws + o);    o += (size_t)M + 8;
  int*      bsum = (int*)(ws + o);    o += 256;
  int2*     csr  = (int2*)(ws + o);   o += (size_t)E * 2;
  ushort_t* rank = (ushort_t*)(ws + o); o += (size_t)E / 2;
  ushort_t* xb   = (ushort_t*)(ws + o); o += (size_t)M * 64;   // bf16 [M][128]
  u8*       xf8  = (u8*)(ws + o);     o += (size_t)M * 32;     // fp8 [M][128]
  ushort_t* tx0b = (ushort_t*)(ws + o); o += (size_t)M * 64;   // bf16 [M][128]
  ushort_t* W1t  = (ushort_t*)(ws + o); o += 40960;
  ushort_t* W2t  = (ushort_t*)(ws + o); o += 35840;
  ushort_t* Wlt  = (ushort_t*)(ws + o); o += 14336;
  u8*       h8   = (u8*)(ws + o);     o += (size_t)M * 160;    // 32MB region: h fp8 [M][320] uses 16MB
  float*    Ar   = ws + o;            o += (size_t)M * 128;    // f32 stride128, 25.6MB
  u8*       Brh  = (u8*)(ws + o);     o += (size_t)M * 32;     // fp8 [M][128]
  u8*       zf8  = (u8*)(ws + o);     o += (size_t)M * 32;     // fp8 [M][128]
  float*    t0   = ws + o;            o += (size_t)M * 2;
  float*    t1   = ws + o;            o += (size_t)M * 2;
  float*    accs = ws + o;            o += 8;
  unsigned* partS = (unsigned*)h8;   // aliases (32MB region), dead during CSR build
  unsigned* partD = (unsigned*)Ar;

  // packing + conversion (one kernel, no memsets anywhere)
  const int n4 = M * 32;
  pack_cvt<<<(n4 + 182272 + 255) / 256, 256, 0, stream>>>(
      x, xb, xf8, n4, W1, W2, l1W, l2W, W1t, W2t, Wlt);

  // CSR build (no global atomics)
  hist2<<<NB_H, 256, 0, stream>>>(src, dst, E, M, partS, partD, rank);
  reduce_base2<<<(2 * PW + 255) / 256, 256, 0, stream>>>(partS, partD, dinv, cnt, M);
  scan_local<<<nb_scan, 256, 0, stream>>>(cnt, ptr, bsum, M);
  scan_bsum<<<1, 256, 0, stream>>>(bsum, nb_scan, accs);
  scan_add<<<nb_scan, 256, 0, stream>>>(ptr, bsum, M, E);
  fill_csr2<<<(E + 255) / 256, 256, 0, stream>>>(src, dst, dinv, ptr, partD, rank, csr, E);

  const int gB = (M + 63) / 64;
  const int gE8 = (M * 8 + 255) / 256;

  // conv1 (h out as fp8)
  gather128e<<<gE8, 256, 0, stream>>>(xf8, tx0b, ptr, csr, M);
  gemm_mfma<0, 320, 256><<<gB, 256, 0, stream>>>(
      xb, tx0b, W1t, b1, nullptr, nullptr, nullptr, nullptr, h8, nullptr, nullptr, nullptr, M);

  // conv2 (A = h fp8)
  gemm_mfma<1, 224, 320><<<gB, 256, 0, stream>>>(
      (const ushort_t*)h8, nullptr, W2t, b2, nullptr, nullptr, nullptr, nullptr,
      Ar, Brh, nullptr, nullptr, M);
  gather100e_x1<<<gE8, 256, 0, stream>>>(Brh, Ar, ptr, csr, M);

  // lins + fused w3
  gemm_mfma<2, 224, 128><<<gB, 256, 0, stream>>>(
      xb, nullptr, Wlt, l1b, l2b, Ar /*x1*/, W3, b3, nullptr, zf8, t0, t1, M);

  // loss (single pass, full rows)
  loss_fp8<<<2048, 256, 0, stream>>>(zf8, ep, en, P, accs);

  // conv3 propagation + final
  gather2_final<<<(M + 255) / 256, 256, 0, stream>>>(t1, t0, ptr, csr,
                                                     accs, c1, c2, out, M, 1.0f / (float)P);
}

// Round 15
// 465.594 us; speedup vs baseline: 1.0788x; 1.0125x over previous
//
#include <hip/hip_runtime.h>
#include <math.h>

// MTGCN R13 = R12 + kernel-merging for overlap (single stream serializes all
// launches, so independent work is merged by block-range):
//   prep   = src-hist (blk 0-255) || dst-hist+rank (blk 256-511) || pack/cvt (rest)
//   loss_g2= loss (blk 0-2047) || gather2 conv3-propagation (blk 2048+)
//   scan   = scan_local + scan_add2 (inline bsum prefix, zeroes accs)
// Rest as R12: fp8 128B rows single-pass eighth-wave, h fp8 [M][320], MFMA GEMMs.

typedef unsigned short ushort_t;
typedef unsigned char u8;
typedef __attribute__((ext_vector_type(8))) __bf16 bf16x8;
typedef __attribute__((ext_vector_type(8))) short s16x8;
typedef __attribute__((ext_vector_type(4))) float f32x4;
typedef __attribute__((ext_vector_type(2))) float f32x2;

#define NB_H 256
#define HW 12500
#define PW 25000
#define LOSS_NB 2048

__device__ __forceinline__ f32x4 mfma16x16x32(s16x8 a, s16x8 b, f32x4 c) {
  return __builtin_amdgcn_mfma_f32_16x16x32_bf16(
      __builtin_bit_cast(bf16x8, a), __builtin_bit_cast(bf16x8, b), c, 0, 0, 0);
}
__device__ __forceinline__ ushort_t f2bf(float f) {
  union { float f; unsigned u; } c; c.f = f;
  unsigned r = (c.u + 0x7FFFu + ((c.u >> 16) & 1u)) >> 16;
  return (ushort_t)r;
}
__device__ __forceinline__ f32x2 cvt2lo(unsigned u) {
  return __builtin_amdgcn_cvt_pk_f32_fp8((int)u, false);
}
__device__ __forceinline__ f32x2 cvt2hi(unsigned u) {
  return __builtin_amdgcn_cvt_pk_f32_fp8((int)u, true);
}
__device__ __forceinline__ u8 f2fp8(float f) {
  return (u8)(__builtin_amdgcn_cvt_pk_fp8_f32(f, 0.f, 0, false) & 0xff);
}

// =======================================================================
// MFMA GEMM (unchanged from R12)
// =======================================================================
template<int VAR, int NT, int KTOT>
__global__ __launch_bounds__(256) void gemm_mfma(
    const ushort_t* __restrict__ A0, const ushort_t* __restrict__ A1,
    const ushort_t* __restrict__ Wt,
    const float* __restrict__ bias0, const float* __restrict__ bias1,
    const float* __restrict__ x1,
    const float* __restrict__ W3c, const float* __restrict__ b3c,
    void* __restrict__ out0, void* __restrict__ out1,
    float* __restrict__ t0g, float* __restrict__ t1g, int M)
{
  constexpr int NF = NT / 32;
  __shared__ __align__(16) ushort_t As[64 * 40];
  __shared__ __align__(16) ushort_t Bs[NT * 40];
  __shared__ float w3s[400];
  const int tid  = threadIdx.x;
  const int lane = tid & 63, w = tid >> 6;
  const int m0 = blockIdx.x * 64;
  const int wm = (w & 1) * 32, wn = (w >> 1) * (NT / 2);
  if (VAR == 2) { for (int i = tid; i < 400; i += 256) w3s[i] = W3c[i]; }
  f32x4 acc[2][NF];
#pragma unroll
  for (int i = 0; i < 2; ++i)
#pragma unroll
    for (int j = 0; j < NF; ++j) acc[i][j] = (f32x4){0.f, 0.f, 0.f, 0.f};

  for (int k0 = 0; k0 < KTOT; k0 += 32) {
    { // A stage
      const int r = tid >> 2, c8 = (tid & 3) * 8;
      const int gm = m0 + r;
      uint4 v = {0u, 0u, 0u, 0u};
      if (gm < M) {
        if (VAR == 1) {  // fp8 h: load 8 bytes, convert to 8 bf16
          const u8* s8 = (const u8*)A0 + (size_t)gm * 320 + k0 + c8;
          const uint2 r8 = *(const uint2*)s8;
          const f32x2 f0 = cvt2lo(r8.x), f1 = cvt2hi(r8.x);
          const f32x2 f2 = cvt2lo(r8.y), f3 = cvt2hi(r8.y);
          v.x = (unsigned)f2bf(f0.x) | ((unsigned)f2bf(f0.y) << 16);
          v.y = (unsigned)f2bf(f1.x) | ((unsigned)f2bf(f1.y) << 16);
          v.z = (unsigned)f2bf(f2.x) | ((unsigned)f2bf(f2.y) << 16);
          v.w = (unsigned)f2bf(f3.x) | ((unsigned)f2bf(f3.y) << 16);
        } else {
          const ushort_t* srcp;
          if (VAR == 0) srcp = (k0 < 128) ? A0 + (size_t)gm * 128 + k0 + c8
                                          : A1 + (size_t)gm * 128 + (k0 - 128) + c8;
          else srcp = A0 + (size_t)gm * 128 + k0 + c8;
          v = *(const uint4*)srcp;
        }
      }
      *(uint4*)&As[r * 40 + c8] = v;
    }
    { // B stage
      const int c8 = (tid & 3) * 8;
#pragma unroll
      for (int i = 0; i < (NT * 4 + 255) / 256; ++i) {
        const int r = (tid >> 2) + i * 64;
        if (r < NT)
          *(uint4*)&Bs[r * 40 + c8] = *(const uint4*)(Wt + (size_t)r * KTOT + k0 + c8);
      }
    }
    __syncthreads();
    s16x8 af[2], bfr[NF];
#pragma unroll
    for (int mi = 0; mi < 2; ++mi)
      af[mi] = *(const s16x8*)&As[(wm + mi * 16 + (lane & 15)) * 40 + (lane >> 4) * 8];
#pragma unroll
    for (int ni = 0; ni < NF; ++ni)
      bfr[ni] = *(const s16x8*)&Bs[(wn + ni * 16 + (lane & 15)) * 40 + (lane >> 4) * 8];
#pragma unroll
    for (int mi = 0; mi < 2; ++mi)
#pragma unroll
      for (int ni = 0; ni < NF; ++ni)
        acc[mi][ni] = mfma16x16x32(af[mi], bfr[ni], acc[mi][ni]);
    __syncthreads();
  }

  if (VAR == 2) {
#pragma unroll
    for (int mi = 0; mi < 2; ++mi)
#pragma unroll
      for (int r = 0; r < 4; ++r) {
        const int gRow = m0 + wm + mi * 16 + ((lane >> 4) << 2) + r;
        float p0 = 0.f, p1 = 0.f, p2 = 0.f, p3 = 0.f;
#pragma unroll
        for (int ni = 0; ni < NF; ++ni) {
          const int col = wn + ni * 16 + (lane & 15);
          const float v = acc[mi][ni][r];
          if (gRow < M) {
            if (col < 100) {
              const float x2v = x1[(size_t)gRow * 128 + col] + fmaxf(v + bias0[col], 0.f);
              p0 = fmaf(x2v, w3s[col * 2 + 0], p0);
              p1 = fmaf(x2v, w3s[col * 2 + 1], p1);
              p2 = fmaf(x2v, w3s[200 + col * 2 + 0], p2);
              p3 = fmaf(x2v, w3s[200 + col * 2 + 1], p3);
            } else if (col < 200) {
              const int c = col - 100;
              ((u8*)out1)[(size_t)gRow * 128 + c] =
                  f2fp8(x1[(size_t)gRow * 128 + c] + fmaxf(v + bias1[c], 0.f));
            }
          }
        }
        if (wn == 0) {
#pragma unroll
          for (int off = 8; off; off >>= 1) {
            p0 += __shfl_down(p0, off, 16);
            p1 += __shfl_down(p1, off, 16);
            p2 += __shfl_down(p2, off, 16);
            p3 += __shfl_down(p3, off, 16);
          }
          if ((lane & 15) == 0 && gRow < M) {
            t0g[(size_t)gRow * 2 + 0] = p0 + b3c[0];
            t0g[(size_t)gRow * 2 + 1] = p1 + b3c[1];
            t1g[(size_t)gRow * 2 + 0] = p2;
            t1g[(size_t)gRow * 2 + 1] = p3;
          }
        }
      }
  } else {
#pragma unroll
    for (int mi = 0; mi < 2; ++mi)
#pragma unroll
      for (int ni = 0; ni < NF; ++ni)
#pragma unroll
        for (int r = 0; r < 4; ++r) {
          const int gRow = m0 + wm + mi * 16 + ((lane >> 4) << 2) + r;
          const int col  = wn + ni * 16 + (lane & 15);
          if (gRow >= M) continue;
          const float v = acc[mi][ni][r];
          if (VAR == 0) {
            ((u8*)out0)[(size_t)gRow * 320 + col] =
                (col < 300) ? f2fp8(fmaxf(v + bias0[col], 0.f)) : (u8)0;
          } else {
            if (col < 100) ((float*)out0)[(size_t)gRow * 128 + col] = v + bias0[col];
            else if (col < 200) ((u8*)out1)[(size_t)gRow * 128 + (col - 100)] = f2fp8(v);
          }
        }
  }
}

// =======================================================================
// prep: merged histogram (src blocks 0-255, dst blocks 256-511 w/ rank) + packing
// =======================================================================
__global__ __launch_bounds__(256) void prep(
    const int* __restrict__ src, const int* __restrict__ dst, int E, int M,
    unsigned* __restrict__ partS, unsigned* __restrict__ partD,
    ushort_t* __restrict__ rank,
    const float* __restrict__ x, ushort_t* __restrict__ xb,
    u8* __restrict__ xf8, int n4,
    const float* __restrict__ W1, const float* __restrict__ W2,
    const float* __restrict__ l1W, const float* __restrict__ l2W,
    ushort_t* __restrict__ W1t, ushort_t* __restrict__ W2t,
    ushort_t* __restrict__ Wlt)
{
  __shared__ unsigned hist[HW];
  const int blk = blockIdx.x;
  if (blk < 512) {
    const int isD = (blk >= 256);
    const int b = isD ? blk - 256 : blk;
    const int* keys = isD ? dst : src;
    unsigned* part = isD ? partD : partS;
    const int cs = (E + NB_H - 1) / NB_H;
    const int e0 = b * cs;
    const int e1 = (e0 + cs < E) ? e0 + cs : E;
    for (int r = 0; r < 2; ++r) {
      const int klo = r * 2 * HW;
      for (int i = threadIdx.x; i < HW; i += 256) hist[i] = 0;
      __syncthreads();
      for (int e = e0 + threadIdx.x; e < e1; e += 256) {
        const int k = keys[e] - klo;
        if ((unsigned)k < (unsigned)(2 * HW)) {
          const unsigned old = atomicAdd(&hist[k >> 1], (k & 1) ? 0x10000u : 1u);
          if (isD) rank[e] = (ushort_t)((old >> ((k & 1) * 16)) & 0xffffu);
        }
      }
      __syncthreads();
      for (int i = threadIdx.x; i < HW; i += 256)
        part[(size_t)b * PW + r * HW + i] = hist[i];
      __syncthreads();
    }
    return;
  }
  // packing section
  const int i = (blk - 512) * 256 + threadIdx.x;
  if (i < n4) {
    const float4 v = ((const float4*)x)[i];
    ushort4 o; o.x = f2bf(v.x); o.y = f2bf(v.y); o.z = f2bf(v.z); o.w = f2bf(v.w);
    ((ushort4*)xb)[i] = o;
    int p = 0;
    p = __builtin_amdgcn_cvt_pk_fp8_f32(v.x, v.y, p, false);
    p = __builtin_amdgcn_cvt_pk_fp8_f32(v.z, v.w, p, true);
    ((unsigned*)xf8)[i] = (unsigned)p;
    return;
  }
  const int j = i - n4;
  if (j < 81920) {                       // W1t [320][256]
    const int n = j >> 8, k = j & 255;
    float v = 0.f;
    if (n < 300) v = (k < 128) ? W1[k * 300 + n] : W1[38400 + (k - 128) * 300 + n];
    W1t[j] = f2bf(v);
  } else if (j < 153600) {               // W2t [224][320]
    const int jj = j - 81920;
    const int n = jj / 320, k = jj - n * 320;
    float v = 0.f;
    if (n < 200 && k < 300) v = W2[(n < 100 ? 0 : 30000) + k * 100 + (n % 100)];
    W2t[jj] = f2bf(v);
  } else if (j < 182272) {               // Wlt [224][128]
    const int jj = j - 153600;
    const int n = jj >> 7, k = jj & 127;
    float v = 0.f;
    if (n < 100) v = l1W[n * 128 + k];
    else if (n < 200) v = l2W[(n - 100) * 128 + k];
    Wlt[jj] = f2bf(v);
  }
}

// ---------------- reduce_base2 (unchanged)
__global__ __launch_bounds__(256) void reduce_base2(
    const unsigned* __restrict__ partS, unsigned* __restrict__ partD,
    float* __restrict__ dinv, int* __restrict__ cnt, int M)
{
  const int t = blockIdx.x * 256 + threadIdx.x;
  if (t < PW) {
    const int i = t;
    unsigned ssum = 0;
    for (int b = 0; b < NB_H; b += 8) {
      unsigned v[8];
#pragma unroll
      for (int q = 0; q < 8; ++q) v[q] = partS[(size_t)(b + q) * PW + i];
#pragma unroll
      for (int q = 0; q < 8; ++q) ssum += v[q];
    }
    const int k = 2 * i;
    const unsigned s0 = ssum & 0xffffu, s1 = ssum >> 16;
    if (k < M) dinv[k] = s0 ? 1.f / sqrtf((float)s0) : 0.f;
    if (k + 1 < M) dinv[k + 1] = s1 ? 1.f / sqrtf((float)s1) : 0.f;
  } else if (t < 2 * PW) {
    const int i = t - PW;
    unsigned run = 0;
    for (int b = 0; b < NB_H; b += 8) {
      unsigned v[8], pre[8];
#pragma unroll
      for (int q = 0; q < 8; ++q) v[q] = partD[(size_t)(b + q) * PW + i];
#pragma unroll
      for (int q = 0; q < 8; ++q) { pre[q] = run; run += v[q]; }
#pragma unroll
      for (int q = 0; q < 8; ++q) partD[(size_t)(b + q) * PW + i] = pre[q];
    }
    const int k = 2 * i;
    if (k < M) cnt[k] = (int)(run & 0xffffu);
    if (k + 1 < M) cnt[k + 1] = (int)(run >> 16);
  }
}

// ---------------- scan: local pass + add pass (inline bsum prefix, accs zero)
__global__ void scan_local(const int* __restrict__ cnt, int* __restrict__ ptr,
                           int* __restrict__ bsum, int n)
{
  __shared__ int tmp[256];
  const int i = blockIdx.x * 256 + threadIdx.x;
  const int v = (i < n) ? cnt[i] : 0;
  tmp[threadIdx.x] = v;
  __syncthreads();
  for (int off = 1; off < 256; off <<= 1) {
    const int t = (threadIdx.x >= off) ? tmp[threadIdx.x - off] : 0;
    __syncthreads();
    tmp[threadIdx.x] += t;
    __syncthreads();
  }
  if (i < n) ptr[i] = tmp[threadIdx.x] - v;
  if (threadIdx.x == 255) bsum[blockIdx.x] = tmp[255];
}
__global__ void scan_add2(int* __restrict__ ptr, const int* __restrict__ bsum,
                          int n, int E, int nb, float* __restrict__ accs)
{
  __shared__ int tmp[256];
  const int v = (threadIdx.x < nb) ? bsum[threadIdx.x] : 0;
  tmp[threadIdx.x] = v;
  __syncthreads();
  for (int off = 1; off < 256; off <<= 1) {
    const int t = (threadIdx.x >= off) ? tmp[threadIdx.x - off] : 0;
    __syncthreads();
    tmp[threadIdx.x] += t;
    __syncthreads();
  }
  __syncthreads();
  const int offset = (blockIdx.x > 0) ? tmp[blockIdx.x - 1] : 0;  // exclusive prefix
  const int i = blockIdx.x * 256 + threadIdx.x;
  if (i < n) ptr[i] += offset;
  if (i == 0) { ptr[n] = E; accs[0] = 0.f; accs[1] = 0.f; }
}

// ---------------- atomic-free fill
__global__ void fill_csr2(const int* __restrict__ src, const int* __restrict__ dst,
                          const float* __restrict__ dinv, const int* __restrict__ ptr,
                          const unsigned* __restrict__ base32,
                          const ushort_t* __restrict__ rank,
                          int2* __restrict__ csr, int E)
{
  const int e = blockIdx.x * 256 + threadIdx.x;
  if (e >= E) return;
  const int cs = (E + NB_H - 1) / NB_H;
  const int b = e / cs;
  const int s = src[e], d = dst[e];
  const unsigned bv = base32[(size_t)b * PW + (d >> 1)];
  const int base = (int)((bv >> ((d & 1) * 16)) & 0xffffu);
  const int pos = ptr[d] + base + (int)rank[e];
  const float w = -dinv[s] * dinv[d];
  csr[pos] = make_int2(s, __float_as_int(w));
}

#define ACCV(u, ww) { f32x2 t; \
  t = cvt2lo(u.x); a[0]  = fmaf(ww, t.x, a[0]);  a[1]  = fmaf(ww, t.y, a[1]);  \
  t = cvt2hi(u.x); a[2]  = fmaf(ww, t.x, a[2]);  a[3]  = fmaf(ww, t.y, a[3]);  \
  t = cvt2lo(u.y); a[4]  = fmaf(ww, t.x, a[4]);  a[5]  = fmaf(ww, t.y, a[5]);  \
  t = cvt2hi(u.y); a[6]  = fmaf(ww, t.x, a[6]);  a[7]  = fmaf(ww, t.y, a[7]);  \
  t = cvt2lo(u.z); a[8]  = fmaf(ww, t.x, a[8]);  a[9]  = fmaf(ww, t.y, a[9]);  \
  t = cvt2hi(u.z); a[10] = fmaf(ww, t.x, a[10]); a[11] = fmaf(ww, t.y, a[11]); \
  t = cvt2lo(u.w); a[12] = fmaf(ww, t.x, a[12]); a[13] = fmaf(ww, t.y, a[13]); \
  t = cvt2hi(u.w); a[14] = fmaf(ww, t.x, a[14]); a[15] = fmaf(ww, t.y, a[15]); }

// ---------------- gather128: eighth-wave, 8-edge unroll
__global__ __launch_bounds__(256) void gather128e(
    const u8* __restrict__ xf8, ushort_t* __restrict__ txb,
    const int* __restrict__ ptr, const int2* __restrict__ csr, int M)
{
  const int node = (blockIdx.x * 256 + threadIdx.x) >> 3;
  const int sub  = threadIdx.x & 7;
  if (node >= M) return;
  const int beg = ptr[node], end = ptr[node + 1];
  float a[16] = {};
  int p = beg;
  for (; p + 8 <= end; p += 8) {
    int2 e[8];
#pragma unroll
    for (int q = 0; q < 8; ++q) e[q] = csr[p + q];
    uint4 v[8];
#pragma unroll
    for (int q = 0; q < 8; ++q)
      v[q] = *(const uint4*)(xf8 + (size_t)e[q].x * 128 + sub * 16);
#pragma unroll
    for (int q = 0; q < 8; ++q) { const float wq = __int_as_float(e[q].y); ACCV(v[q], wq) }
  }
  for (; p < end; ++p) {
    const int2 eq = csr[p]; const float wq = __int_as_float(eq.y);
    const uint4 v = *(const uint4*)(xf8 + (size_t)eq.x * 128 + sub * 16);
    ACCV(v, wq)
  }
  uint4 o1, o2;
  o1.x = (unsigned)f2bf(a[0])  | ((unsigned)f2bf(a[1])  << 16);
  o1.y = (unsigned)f2bf(a[2])  | ((unsigned)f2bf(a[3])  << 16);
  o1.z = (unsigned)f2bf(a[4])  | ((unsigned)f2bf(a[5])  << 16);
  o1.w = (unsigned)f2bf(a[6])  | ((unsigned)f2bf(a[7])  << 16);
  o2.x = (unsigned)f2bf(a[8])  | ((unsigned)f2bf(a[9])  << 16);
  o2.y = (unsigned)f2bf(a[10]) | ((unsigned)f2bf(a[11]) << 16);
  o2.z = (unsigned)f2bf(a[12]) | ((unsigned)f2bf(a[13]) << 16);
  o2.w = (unsigned)f2bf(a[14]) | ((unsigned)f2bf(a[15]) << 16);
  ushort_t* dstp = txb + (size_t)node * 128 + sub * 16;
  *(uint4*)dstp = o1;
  *(uint4*)(dstp + 8) = o2;
}

// ---------------- fused gather100 + x1 (eighth-wave, 8-edge unroll)
__global__ __launch_bounds__(256) void gather100e_x1(
    const u8* __restrict__ Brh, float* __restrict__ Ar,
    const int* __restrict__ ptr, const int2* __restrict__ csr, int M)
{
  const int node = (blockIdx.x * 256 + threadIdx.x) >> 3;
  const int sub  = threadIdx.x & 7;
  if (node >= M) return;
  const int beg = ptr[node], end = ptr[node + 1];
  float a[16] = {};
  int p = beg;
  for (; p + 8 <= end; p += 8) {
    int2 e[8];
#pragma unroll
    for (int q = 0; q < 8; ++q) e[q] = csr[p + q];
    uint4 v[8];
#pragma unroll
    for (int q = 0; q < 8; ++q)
      v[q] = *(const uint4*)(Brh + (size_t)e[q].x * 128 + sub * 16);
#pragma unroll
    for (int q = 0; q < 8; ++q) { const float wq = __int_as_float(e[q].y); ACCV(v[q], wq) }
  }
  for (; p < end; ++p) {
    const int2 eq = csr[p]; const float wq = __int_as_float(eq.y);
    const uint4 v = *(const uint4*)(Brh + (size_t)eq.x * 128 + sub * 16);
    ACCV(v, wq)
  }
  float* dstp = Ar + (size_t)node * 128 + sub * 16;
#pragma unroll
  for (int q = 0; q < 4; ++q) {
    float4 b = *(const float4*)(dstp + q * 4);
    b.x = fmaxf(b.x + a[q * 4 + 0], 0.f);
    b.y = fmaxf(b.y + a[q * 4 + 1], 0.f);
    b.z = fmaxf(b.z + a[q * 4 + 2], 0.f);
    b.w = fmaxf(b.w + a[q * 4 + 3], 0.f);
    *(float4*)(dstp + q * 4) = b;
  }
}
#undef ACCV

// ---------------- merged loss + gather2: loss blocks [0,LOSS_NB), gather2 after
__device__ __forceinline__ void maskrow(uint4& r, int sub) {
  if (sub >= 6) { r.y = 0u; r.z = 0u; r.w = 0u; if (sub == 7) r.x = 0u; }
}
#define DOTV(uu, vv, s) { f32x2 p_, q_; \
  p_ = cvt2lo(uu.x); q_ = cvt2lo(vv.x); s = fmaf(p_.x, q_.x, s); s = fmaf(p_.y, q_.y, s); \
  p_ = cvt2hi(uu.x); q_ = cvt2hi(vv.x); s = fmaf(p_.x, q_.x, s); s = fmaf(p_.y, q_.y, s); \
  p_ = cvt2lo(uu.y); q_ = cvt2lo(vv.y); s = fmaf(p_.x, q_.x, s); s = fmaf(p_.y, q_.y, s); \
  p_ = cvt2hi(uu.y); q_ = cvt2hi(vv.y); s = fmaf(p_.x, q_.x, s); s = fmaf(p_.y, q_.y, s); \
  p_ = cvt2lo(uu.z); q_ = cvt2lo(vv.z); s = fmaf(p_.x, q_.x, s); s = fmaf(p_.y, q_.y, s); \
  p_ = cvt2hi(uu.z); q_ = cvt2hi(vv.z); s = fmaf(p_.x, q_.x, s); s = fmaf(p_.y, q_.y, s); \
  p_ = cvt2lo(uu.w); q_ = cvt2lo(vv.w); s = fmaf(p_.x, q_.x, s); s = fmaf(p_.y, q_.y, s); \
  p_ = cvt2hi(uu.w); q_ = cvt2hi(vv.w); s = fmaf(p_.x, q_.x, s); s = fmaf(p_.y, q_.y, s); }

__global__ __launch_bounds__(256) void loss_g2(
    const u8* __restrict__ zf8, const int* __restrict__ ep,
    const int* __restrict__ en, int P, float* __restrict__ acc,
    const float* __restrict__ t1, const float* __restrict__ t0,
    const int* __restrict__ ptr, const int2* __restrict__ csr,
    float* __restrict__ out, int M)
{
  const int tid = threadIdx.x;
  if (blockIdx.x >= LOSS_NB) {
    // ---- gather2 section: out[i*2..] = t0[i] + L_hat(t1)[i]
    const int i = (blockIdx.x - LOSS_NB) * 256 + tid;
    if (i >= M) return;
    float a0 = 0.f, a1 = 0.f;
    const int beg = ptr[i], end = ptr[i + 1];
    int p = beg;
    for (; p + 4 <= end; p += 4) {
      const int2 e0 = csr[p], e1 = csr[p + 1], e2 = csr[p + 2], e3 = csr[p + 3];
      const float w0 = __int_as_float(e0.y), w1 = __int_as_float(e1.y);
      const float w2 = __int_as_float(e2.y), w3 = __int_as_float(e3.y);
      const float2 v0 = *(const float2*)(t1 + (size_t)e0.x * 2);
      const float2 v1 = *(const float2*)(t1 + (size_t)e1.x * 2);
      const float2 v2 = *(const float2*)(t1 + (size_t)e2.x * 2);
      const float2 v3 = *(const float2*)(t1 + (size_t)e3.x * 2);
      a0 = fmaf(w0, v0.x, a0); a1 = fmaf(w0, v0.y, a1);
      a0 = fmaf(w1, v1.x, a0); a1 = fmaf(w1, v1.y, a1);
      a0 = fmaf(w2, v2.x, a0); a1 = fmaf(w2, v2.y, a1);
      a0 = fmaf(w3, v3.x, a0); a1 = fmaf(w3, v3.y, a1);
    }
    for (; p < end; ++p) {
      const int2 eq = csr[p]; const float wq = __int_as_float(eq.y);
      const float2 v = *(const float2*)(t1 + (size_t)eq.x * 2);
      a0 = fmaf(wq, v.x, a0); a1 = fmaf(wq, v.y, a1);
    }
    const float2 base = *(const float2*)(t0 + (size_t)i * 2);
    *(float2*)(out + (size_t)i * 2) = make_float2(base.x + a0, base.y + a1);
    return;
  }
  // ---- loss section
  __shared__ float red[8];
  const int lane = tid & 63, wib = tid >> 6;
  const int sub = tid & 7;
  const int slot0 = blockIdx.x * 32 + (tid >> 3);
  const int step = LOSS_NB * 32;
  float tp = 0.f, tn = 0.f;
  int g = slot0;
  for (; g + 3 * step < 2 * P; g += 4 * step) {
    int neg[4], na[4], nb[4];
#pragma unroll
    for (int q = 0; q < 4; ++q) {
      const int gq = g + q * step;
      neg[q] = (gq >= P);
      const int p = neg[q] ? gq - P : gq;
      const int* ia = neg[q] ? en : ep;
      na[q] = ia[p]; nb[q] = ia[P + p];
    }
    uint4 ra[4], rb[4];
#pragma unroll
    for (int q = 0; q < 4; ++q) {
      ra[q] = *(const uint4*)(zf8 + (size_t)na[q] * 128 + sub * 16);
      rb[q] = *(const uint4*)(zf8 + (size_t)nb[q] * 128 + sub * 16);
      maskrow(ra[q], sub); maskrow(rb[q], sub);
    }
    float s[4] = {0.f, 0.f, 0.f, 0.f};
#pragma unroll
    for (int q = 0; q < 4; ++q) DOTV(ra[q], rb[q], s[q])
#pragma unroll
    for (int off = 4; off; off >>= 1) {
#pragma unroll
      for (int q = 0; q < 4; ++q) s[q] += __shfl_down(s[q], off, 8);
    }
    if (sub == 0) {
#pragma unroll
      for (int q = 0; q < 4; ++q) {
        const float sig = 1.f / (1.f + expf(-s[q]));
        if (neg[q]) tn += logf(1.f - sig + 1e-15f); else tp += logf(sig + 1e-15f);
      }
    }
  }
  for (; g < 2 * P; g += step) {
    const int neg = (g >= P);
    const int p = neg ? g - P : g;
    const int* ia = neg ? en : ep;
    const int na = ia[p], nb = ia[P + p];
    uint4 ra = *(const uint4*)(zf8 + (size_t)na * 128 + sub * 16);
    uint4 rb = *(const uint4*)(zf8 + (size_t)nb * 128 + sub * 16);
    maskrow(ra, sub); maskrow(rb, sub);
    float s = 0.f;
    DOTV(ra, rb, s)
#pragma unroll
    for (int off = 4; off; off >>= 1) s += __shfl_down(s, off, 8);
    if (sub == 0) {
      const float sig = 1.f / (1.f + expf(-s));
      if (neg) tn += logf(1.f - sig + 1e-15f); else tp += logf(sig + 1e-15f);
    }
  }
  tp += __shfl_down(tp, 32, 64); tn += __shfl_down(tn, 32, 64);
  tp += __shfl_down(tp, 16, 64); tn += __shfl_down(tn, 16, 64);
  tp += __shfl_down(tp, 8, 64);  tn += __shfl_down(tn, 8, 64);
  if (lane == 0) { red[wib] = tp; red[4 + wib] = tn; }
  __syncthreads();
  if (tid == 0) {
    atomicAdd(acc + 0, red[0] + red[1] + red[2] + red[3]);
    atomicAdd(acc + 1, red[4] + red[5] + red[6] + red[7]);
  }
}
#undef DOTV

// ---------------- final scalars (needs accs complete)
__global__ void final_scalars(const float* __restrict__ accs,
                              const float* __restrict__ c1, const float* __restrict__ c2,
                              float* __restrict__ out, int M, float invP)
{
  out[2 * M + 0] = -(accs[0] + accs[1]) * invP;
  out[2 * M + 1] = c1[0];
  out[2 * M + 2] = c2[0];
}

extern "C" void kernel_launch(void* const* d_in, const int* in_sizes, int n_in,
                              void* d_out, int out_size, void* d_ws, size_t ws_size,
                              hipStream_t stream)
{
  const float* x   = (const float*)d_in[0];
  const int*   ei  = (const int*)d_in[1];
  const int*   ep  = (const int*)d_in[2];
  const int*   en  = (const int*)d_in[3];
  const float* W1  = (const float*)d_in[4];
  const float* b1  = (const float*)d_in[5];
  const float* W2  = (const float*)d_in[6];
  const float* b2  = (const float*)d_in[7];
  const float* W3  = (const float*)d_in[8];
  const float* b3  = (const float*)d_in[9];
  const float* l1W = (const float*)d_in[10];
  const float* l1b = (const float*)d_in[11];
  const float* l2W = (const float*)d_in[12];
  const float* l2b = (const float*)d_in[13];
  const float* c1  = (const float*)d_in[14];
  const float* c2  = (const float*)d_in[15];
  float* out = (float*)d_out;

  const int M = in_sizes[0] / 128;  // 50000
  const int E = in_sizes[1] / 2;    // 800000
  const int P = in_sizes[2] / 2;    // 400000
  const int* src = ei;
  const int* dst = ei + E;
  const int nb_scan = (M + 255) / 256;

  float* ws = (float*)d_ws;
  size_t o = 0;
  float*    dinv = ws + o;            o += 50176;
  int*      cnt  = (int*)(ws + o);    o += (size_t)M;
  int*      ptr  = (int*)(ws + o);    o += (size_t)M + 8;
  int*      bsum = (int*)(ws + o);    o += 256;
  int2*     csr  = (int2*)(ws + o);   o += (size_t)E * 2;
  ushort_t* rank = (ushort_t*)(ws + o); o += (size_t)E / 2;
  ushort_t* xb   = (ushort_t*)(ws + o); o += (size_t)M * 64;   // bf16 [M][128]
  u8*       xf8  = (u8*)(ws + o);     o += (size_t)M * 32;     // fp8 [M][128]
  ushort_t* tx0b = (ushort_t*)(ws + o); o += (size_t)M * 64;   // bf16 [M][128]
  ushort_t* W1t  = (ushort_t*)(ws + o); o += 40960;
  ushort_t* W2t  = (ushort_t*)(ws + o); o += 35840;
  ushort_t* Wlt  = (ushort_t*)(ws + o); o += 14336;
  u8*       h8   = (u8*)(ws + o);     o += (size_t)M * 160;    // 32MB region: h fp8 uses 16MB
  float*    Ar   = ws + o;            o += (size_t)M * 128;    // f32 stride128, 25.6MB
  u8*       Brh  = (u8*)(ws + o);     o += (size_t)M * 32;     // fp8 [M][128]
  u8*       zf8  = (u8*)(ws + o);     o += (size_t)M * 32;     // fp8 [M][128]
  float*    t0   = ws + o;            o += (size_t)M * 2;
  float*    t1   = ws + o;            o += (size_t)M * 2;
  float*    accs = ws + o;            o += 8;
  unsigned* partS = (unsigned*)h8;   // aliases (32MB region), dead during CSR build
  unsigned* partD = (unsigned*)Ar;

  // prep: hist(src) || hist(dst)+rank || packing — all input-only
  const int n4 = M * 32;
  const int packBlocks = (n4 + 182272 + 255) / 256;
  prep<<<512 + packBlocks, 256, 0, stream>>>(
      src, dst, E, M, partS, partD, rank,
      x, xb, xf8, n4, W1, W2, l1W, l2W, W1t, W2t, Wlt);

  // CSR build (no global atomics)
  reduce_base2<<<(2 * PW + 255) / 256, 256, 0, stream>>>(partS, partD, dinv, cnt, M);
  scan_local<<<nb_scan, 256, 0, stream>>>(cnt, ptr, bsum, M);
  scan_add2<<<nb_scan, 256, 0, stream>>>(ptr, bsum, M, E, nb_scan, accs);
  fill_csr2<<<(E + 255) / 256, 256, 0, stream>>>(src, dst, dinv, ptr, partD, rank, csr, E);

  const int gB = (M + 63) / 64;
  const int gE8 = (M * 8 + 255) / 256;

  // conv1 (h out as fp8)
  gather128e<<<gE8, 256, 0, stream>>>(xf8, tx0b, ptr, csr, M);
  gemm_mfma<0, 320, 256><<<gB, 256, 0, stream>>>(
      xb, tx0b, W1t, b1, nullptr, nullptr, nullptr, nullptr, h8, nullptr, nullptr, nullptr, M);

  // conv2 (A = h fp8)
  gemm_mfma<1, 224, 320><<<gB, 256, 0, stream>>>(
      (const ushort_t*)h8, nullptr, W2t, b2, nullptr, nullptr, nullptr, nullptr,
      Ar, Brh, nullptr, nullptr, M);
  gather100e_x1<<<gE8, 256, 0, stream>>>(Brh, Ar, ptr, csr, M);

  // lins + fused w3
  gemm_mfma<2, 224, 128><<<gB, 256, 0, stream>>>(
      xb, nullptr, Wlt, l1b, l2b, Ar /*x1*/, W3, b3, nullptr, zf8, t0, t1, M);

  // loss || conv3 propagation (independent), then scalars
  loss_g2<<<LOSS_NB + nb_scan, 256, 0, stream>>>(
      zf8, ep, en, P, accs, t1, t0, ptr, csr, out, M);
  final_scalars<<<1, 1, 0, stream>>>(accs, c1, c2, out, M, 1.0f / (float)P);
}